// Round 1
// baseline (1910.524 us; speedup 1.0000x reference)
//
#include <hip/hip_runtime.h>
#include <hip/hip_bf16.h>

// Problem constants (DeltaNet_6614249636545)
#define BB 2
#define TT 4096
#define HH 16
#define DKk 128
#define DVv 128
#define HIDD 2048
#define CC 64
#define NN 64          // TT / CC
#define GG 8           // dv column groups in scan kernel
#define QSCALE 0.08838834764831845f  // 128^-0.5

static __device__ __forceinline__ unsigned short f2bf(float f) {
  unsigned u = __float_as_uint(f);
  u += 0x7fffu + ((u >> 16) & 1u);   // round-to-nearest-even
  return (unsigned short)(u >> 16);
}
static __device__ __forceinline__ float bf2f(unsigned short s) {
  return __uint_as_float(((unsigned)s) << 16);
}

// ---------------------------------------------------------------------------
// K1: beta = sigmoid(hidden_ab @ Wb), graw = hidden_g @ Wg   (one block/token)
// ---------------------------------------------------------------------------
__global__ __launch_bounds__(256) void k1_beta_g(
    const float* __restrict__ hab, const float* __restrict__ hg,
    const float* __restrict__ Wb, const float* __restrict__ Wg,
    float* __restrict__ beta, float* __restrict__ graw) {
  int token = blockIdx.x;
  int tid = threadIdx.x;
  const float* pa = hab + (size_t)token * HIDD;
  const float* pg = hg + (size_t)token * HIDD;
  float accb[HH], accg[HH];
#pragma unroll
  for (int h = 0; h < HH; h++) { accb[h] = 0.f; accg[h] = 0.f; }
  for (int r = 0; r < 2; r++) {
    int i = r * 1024 + tid * 4;
    float4 xa = *(const float4*)(pa + i);
    float4 xg = *(const float4*)(pg + i);
    float av[4] = {xa.x, xa.y, xa.z, xa.w};
    float gv[4] = {xg.x, xg.y, xg.z, xg.w};
#pragma unroll
    for (int s = 0; s < 4; s++) {
      const float* wb = Wb + (size_t)(i + s) * HH;
      const float* wg = Wg + (size_t)(i + s) * HH;
#pragma unroll
      for (int h = 0; h < HH; h++) { accb[h] += av[s] * wb[h]; accg[h] += gv[s] * wg[h]; }
    }
  }
  __shared__ float red[32][257];
#pragma unroll
  for (int h = 0; h < HH; h++) { red[h][tid] = accb[h]; red[HH + h][tid] = accg[h]; }
  __syncthreads();
  int row = tid >> 3, l8 = tid & 7;
  float p = 0.f;
  for (int j = 0; j < 32; j++) p += red[row][l8 + 8 * j];
  p += __shfl_down(p, 4, 8);
  p += __shfl_down(p, 2, 8);
  p += __shfl_down(p, 1, 8);
  if (l8 == 0) {
    if (row < HH) beta[(size_t)token * HH + row] = 1.f / (1.f + expf(-p));
    else          graw[(size_t)token * HH + (row - HH)] = p;
  }
}

// ---------------------------------------------------------------------------
// K2: l2norm(q)*scale -> qn (bf16), l2norm(k) -> kn (bf16)
// one wave handles 2 vectors (for both q and k); block=256 -> 8 vectors
// ---------------------------------------------------------------------------
__global__ __launch_bounds__(256) void k2_l2norm(
    const float* __restrict__ q, const float* __restrict__ k,
    unsigned short* __restrict__ qn, unsigned short* __restrict__ kn) {
  int lane = threadIdx.x & 63, wave = threadIdx.x >> 6;
  for (int u = 0; u < 2; u++) {
    int vec = blockIdx.x * 8 + wave * 2 + u;
    size_t off = (size_t)vec * 64 + lane;
    float2 q2 = ((const float2*)q)[off];
    float2 k2 = ((const float2*)k)[off];
    float sq = q2.x * q2.x + q2.y * q2.y;
    float sk = k2.x * k2.x + k2.y * k2.y;
#pragma unroll
    for (int m = 32; m; m >>= 1) { sq += __shfl_xor(sq, m); sk += __shfl_xor(sk, m); }
    float rq = rsqrtf(sq + 1e-6f) * QSCALE;
    float rk = rsqrtf(sk + 1e-6f);
    unsigned pq = (unsigned)f2bf(q2.x * rq) | ((unsigned)f2bf(q2.y * rq) << 16);
    unsigned pk = (unsigned)f2bf(k2.x * rk) | ((unsigned)f2bf(k2.y * rk) << 16);
    ((unsigned*)qn)[off] = pq;
    ((unsigned*)kn)[off] = pk;
  }
}

// ---------------------------------------------------------------------------
// K3: per chunk (b,h,n): attn = tril(q k^T) -> global,
//     A = tril(k_beta k^T,-1);  T = (I+A)^{-1} -> global (bf16)
// block = 256 threads, one block per chunk. cid = (b*H+h)*N + n
// ---------------------------------------------------------------------------
__global__ __launch_bounds__(256) void k3_chunk(
    const unsigned short* __restrict__ qn, const unsigned short* __restrict__ kn,
    const float* __restrict__ beta,
    unsigned short* __restrict__ Tg, unsigned short* __restrict__ Ag) {
  int cid = blockIdx.x;
  int n = cid & (NN - 1);
  int bh = cid / NN;
  int h = bh & (HH - 1);
  int b = bh / HH;
  int tid = threadIdx.x;

  __shared__ __align__(16) unsigned short sk[CC * 129];   // 16512 B
  __shared__ __align__(16) unsigned short sq[CC * 129];   // 16512 B
  __shared__ __align__(16) unsigned short sA[CC * 65];    //  8320 B
  __shared__ __align__(16) float sM[CC * 65];             // 16640 B
  __shared__ float sb[CC];

  int t0 = n * CC;
  // stage k,q (bf16 raw copy), beta; init M = I
  for (int r = 0; r < 8; r++) {
    int idx4 = r * 256 + tid;            // 2048 quads
    int c = idx4 >> 5;
    int d4 = (idx4 & 31) << 2;
    size_t g = ((size_t)((b * TT + t0 + c) * HH + h)) * DKk + d4;
    ushort4 vk = *(const ushort4*)(kn + g);
    ushort4 vq = *(const ushort4*)(qn + g);
    int o = c * 129 + d4;
    sk[o] = vk.x; sk[o + 1] = vk.y; sk[o + 2] = vk.z; sk[o + 3] = vk.w;
    sq[o] = vq.x; sq[o + 1] = vq.y; sq[o + 2] = vq.z; sq[o + 3] = vq.w;
  }
  if (tid < CC) sb[tid] = beta[(size_t)((b * TT + t0 + tid) * HH + h)];
  for (int r = 0; r < 16; r++) {
    int idx = r * 256 + tid;
    int i = idx >> 6, j = idx & 63;
    sM[i * 65 + j] = (i == j) ? 1.f : 0.f;
  }
  __syncthreads();

  int iq = tid >> 4, jqt = tid & 15;
  int i0 = iq << 2, j0 = jqt << 2;
  size_t abase = (size_t)cid * (CC * CC);

  // attn = tril(q k^T, 0) -> global bf16 (upper zeros)
  {
    float acc[4][4];
#pragma unroll
    for (int a = 0; a < 4; a++)
#pragma unroll
      for (int e = 0; e < 4; e++) acc[a][e] = 0.f;
    if (j0 <= i0 + 3) {
      for (int d = 0; d < DKk; d++) {
        float qv[4], kv[4];
#pragma unroll
        for (int a = 0; a < 4; a++) qv[a] = bf2f(sq[(i0 + a) * 129 + d]);
#pragma unroll
        for (int e = 0; e < 4; e++) kv[e] = bf2f(sk[(j0 + e) * 129 + d]);
#pragma unroll
        for (int a = 0; a < 4; a++)
#pragma unroll
          for (int e = 0; e < 4; e++) acc[a][e] += qv[a] * kv[e];
      }
    }
#pragma unroll
    for (int a = 0; a < 4; a++)
#pragma unroll
      for (int e = 0; e < 4; e++) {
        int i = i0 + a, j = j0 + e;
        Ag[abase + i * CC + j] = f2bf((j <= i) ? acc[a][e] : 0.f);
      }
  }
  // A = tril(k_beta k^T, -1) -> LDS bf16 (upper+diag zeros)
  {
    float acc[4][4];
#pragma unroll
    for (int a = 0; a < 4; a++)
#pragma unroll
      for (int e = 0; e < 4; e++) acc[a][e] = 0.f;
    if (j0 <= i0 + 3) {
      for (int d = 0; d < DKk; d++) {
        float ki[4], kj[4];
#pragma unroll
        for (int a = 0; a < 4; a++) ki[a] = bf2f(sk[(i0 + a) * 129 + d]);
#pragma unroll
        for (int e = 0; e < 4; e++) kj[e] = bf2f(sk[(j0 + e) * 129 + d]);
#pragma unroll
        for (int a = 0; a < 4; a++)
#pragma unroll
          for (int e = 0; e < 4; e++) acc[a][e] += ki[a] * kj[e];
      }
    }
#pragma unroll
    for (int a = 0; a < 4; a++)
#pragma unroll
      for (int e = 0; e < 4; e++) {
        int i = i0 + a, j = j0 + e;
        sA[i * 65 + j] = f2bf((j < i) ? sb[i] * acc[a][e] : 0.f);
      }
  }
  __syncthreads();

  // T = (I+A)^{-1}: lane j owns column j (no cross-lane deps)
  if (tid < CC) {
    int j = tid;
    for (int i = j + 1; i < CC; i++) {
      float s = bf2f(sA[i * 65 + j]);
      for (int kk = j + 1; kk < i; kk++)
        s += bf2f(sA[i * 65 + kk]) * sM[kk * 65 + j];
      sM[i * 65 + j] = -s;
    }
  }
  __syncthreads();

  for (int r = 0; r < 16; r++) {
    int idx = r * 256 + tid;
    int i = idx >> 6, j = idx & 63;
    Tg[abase + idx] = f2bf(sM[i * 65 + j]);
  }
}

// ---------------------------------------------------------------------------
// K4: sequential chunk scan. block = (b,h,jg) handling 16 DV columns.
//   x  = beta_c * (v - k @ S)           [C x 16]
//   vi = T @ x                          [C x 16]
//   o  = q @ S + attn @ vi  -> d_out    [C x 16]
//   S += k^T @ vi                       [DK x 16]  (fp32 in LDS)
// ---------------------------------------------------------------------------
__global__ __launch_bounds__(256) void k4_scan(
    const unsigned short* __restrict__ qn, const unsigned short* __restrict__ kn,
    const float* __restrict__ v, const float* __restrict__ beta,
    const unsigned short* __restrict__ Tg, const unsigned short* __restrict__ Ag,
    float* __restrict__ o) {
  int bi = blockIdx.x;                 // B*H*G = 256
  int jg = bi & (GG - 1);
  int h = (bi >> 3) & (HH - 1);
  int b = bi >> 7;
  int tid = threadIdx.x;
  int j0 = jg * 16;

  __shared__ __align__(16) unsigned short sk[CC * 129];  // 16512 B
  __shared__ __align__(16) unsigned short sq[CC * 129];  // 16512 B
  __shared__ __align__(16) unsigned short sT[CC * 65];   //  8320 B
  __shared__ __align__(16) unsigned short sA[CC * 65];   //  8320 B
  __shared__ __align__(16) float sS[DKk * 16];           //  8192 B
  __shared__ __align__(16) unsigned short sx[CC * 16];   //  2048 B
  __shared__ __align__(16) float svi[CC * 16];           //  4096 B
  __shared__ float sb[CC];                               //   256 B  (total 64256)

  for (int r = tid; r < DKk * 16; r += 256) sS[r] = 0.f;
  __syncthreads();

  int c = tid >> 2, jq = tid & 3;
  int bhBase = (b * HH + h) * NN;

  for (int n = 0; n < NN; n++) {
    int t0 = n * CC;
    // ---- stage k, q, T, attn, beta
    for (int r = 0; r < 8; r++) {
      int idx4 = r * 256 + tid;
      int cc2 = idx4 >> 5;
      int d4 = (idx4 & 31) << 2;
      size_t g = ((size_t)((b * TT + t0 + cc2) * HH + h)) * DKk + d4;
      ushort4 vk = *(const ushort4*)(kn + g);
      ushort4 vq = *(const ushort4*)(qn + g);
      int oo = cc2 * 129 + d4;
      sk[oo] = vk.x; sk[oo + 1] = vk.y; sk[oo + 2] = vk.z; sk[oo + 3] = vk.w;
      sq[oo] = vq.x; sq[oo + 1] = vq.y; sq[oo + 2] = vq.z; sq[oo + 3] = vq.w;
    }
    {
      size_t cb = (size_t)(bhBase + n) * (CC * CC);
      for (int r = 0; r < 4; r++) {
        int idx4 = r * 256 + tid;
        int i = idx4 >> 4;
        int j4 = (idx4 & 15) << 2;
        ushort4 vt = *(const ushort4*)(Tg + cb + i * CC + j4);
        ushort4 va = *(const ushort4*)(Ag + cb + i * CC + j4);
        int oo = i * 65 + j4;
        sT[oo] = vt.x; sT[oo + 1] = vt.y; sT[oo + 2] = vt.z; sT[oo + 3] = vt.w;
        sA[oo] = va.x; sA[oo + 1] = va.y; sA[oo + 2] = va.z; sA[oo + 3] = va.w;
      }
    }
    if (tid < CC) sb[tid] = beta[(size_t)((b * TT + t0 + tid) * HH + h)];
    __syncthreads();

    // ---- x = beta_c * (v - k@S)   (store bf16)
    {
      float a0 = 0, a1 = 0, a2 = 0, a3 = 0;
      for (int d = 0; d < DKk; d++) {
        float kv = bf2f(sk[c * 129 + d]);
        const float4 s4 = *(const float4*)&sS[(d << 4) + (jq << 2)];
        a0 += kv * s4.x; a1 += kv * s4.y; a2 += kv * s4.z; a3 += kv * s4.w;
      }
      size_t gv = ((size_t)((b * TT + t0 + c) * HH + h)) * DVv + j0 + (jq << 2);
      const float4 vv = *(const float4*)(v + gv);
      float bc = sb[c];
      unsigned p0 = (unsigned)f2bf(bc * (vv.x - a0)) | ((unsigned)f2bf(bc * (vv.y - a1)) << 16);
      unsigned p1 = (unsigned)f2bf(bc * (vv.z - a2)) | ((unsigned)f2bf(bc * (vv.w - a3)) << 16);
      *(uint2*)&sx[(c << 4) + (jq << 2)] = make_uint2(p0, p1);
    }
    __syncthreads();

    // ---- vi = T @ x   (store fp32)
    {
      float a0 = 0, a1 = 0, a2 = 0, a3 = 0;
      for (int m = 0; m < CC; m++) {
        float tv = bf2f(sT[c * 65 + m]);
        uint2 u = *(const uint2*)&sx[(m << 4) + (jq << 2)];
        a0 += tv * __uint_as_float(u.x << 16);
        a1 += tv * __uint_as_float(u.x & 0xffff0000u);
        a2 += tv * __uint_as_float(u.y << 16);
        a3 += tv * __uint_as_float(u.y & 0xffff0000u);
      }
      float4 r; r.x = a0; r.y = a1; r.z = a2; r.w = a3;
      *(float4*)&svi[(c << 4) + (jq << 2)] = r;
    }
    __syncthreads();

    // ---- o = q@S + attn@vi -> global (uses OLD S)
    {
      float a0 = 0, a1 = 0, a2 = 0, a3 = 0;
      for (int d = 0; d < DKk; d++) {
        float qv = bf2f(sq[c * 129 + d]);
        const float4 s4 = *(const float4*)&sS[(d << 4) + (jq << 2)];
        a0 += qv * s4.x; a1 += qv * s4.y; a2 += qv * s4.z; a3 += qv * s4.w;
      }
      for (int m = 0; m < CC; m++) {
        float av = bf2f(sA[c * 65 + m]);
        const float4 vi4 = *(const float4*)&svi[(m << 4) + (jq << 2)];
        a0 += av * vi4.x; a1 += av * vi4.y; a2 += av * vi4.z; a3 += av * vi4.w;
      }
      size_t go = ((size_t)((b * TT + t0 + c) * HH + h)) * DVv + j0 + (jq << 2);
      float4 r; r.x = a0; r.y = a1; r.z = a2; r.w = a3;
      *(float4*)(o + go) = r;
    }
    __syncthreads();

    // ---- S += k^T @ vi
    {
      int d2 = tid >> 2;   // 0..63; handles rows d2 and d2+64
      float a0 = 0, a1 = 0, a2 = 0, a3 = 0, b0 = 0, b1 = 0, b2 = 0, b3 = 0;
      for (int m = 0; m < CC; m++) {
        float k1 = bf2f(sk[m * 129 + d2]);
        float k2 = bf2f(sk[m * 129 + 64 + d2]);
        const float4 vi4 = *(const float4*)&svi[(m << 4) + (jq << 2)];
        a0 += k1 * vi4.x; a1 += k1 * vi4.y; a2 += k1 * vi4.z; a3 += k1 * vi4.w;
        b0 += k2 * vi4.x; b1 += k2 * vi4.y; b2 += k2 * vi4.z; b3 += k2 * vi4.w;
      }
      float4* p0 = (float4*)&sS[(d2 << 4) + (jq << 2)];
      float4* p1 = (float4*)&sS[((d2 + 64) << 4) + (jq << 2)];
      float4 t0v = *p0; t0v.x += a0; t0v.y += a1; t0v.z += a2; t0v.w += a3; *p0 = t0v;
      float4 t1v = *p1; t1v.x += b0; t1v.y += b1; t1v.z += b2; t1v.w += b3; *p1 = t1v;
    }
    __syncthreads();
  }
}

// ---------------------------------------------------------------------------
// K5: in-place on d_out: RMSNorm(o)*o_norm_w * swish(g), then per-head
//     projection out[t, h*128+d] = sum_v o~[v] * P[h,v,d].
// block = (b, 32-token tile, h); stages o rows to LDS before overwriting.
// ---------------------------------------------------------------------------
__global__ __launch_bounds__(256) void k5_out(
    const float* __restrict__ graw, const float* __restrict__ onw,
    const float* __restrict__ opw, float* __restrict__ out) {
  int bi = blockIdx.x;                  // B*(T/32)*H = 4096
  int h = bi & (HH - 1);
  int tt = (bi >> 4) & 127;
  int b = bi >> 11;
  int t0 = tt * 32;
  int tid = threadIdx.x;

  __shared__ __align__(16) unsigned short sP[DVv * DKk];  // 32768 B (bf16)
  __shared__ __align__(16) float so[32 * 129];            // 16512 B
  __shared__ float smul[32];
  __shared__ float snw[DVv];

  const float* P = opw + (size_t)h * DVv * DKk;
  for (int r = 0; r < 16; r++) {
    int idx4 = r * 256 + tid;           // 4096 quads
    float4 pv = *(const float4*)(P + ((size_t)idx4 << 2));
    unsigned p0 = (unsigned)f2bf(pv.x) | ((unsigned)f2bf(pv.y) << 16);
    unsigned p1 = (unsigned)f2bf(pv.z) | ((unsigned)f2bf(pv.w) << 16);
    *(uint2*)&sP[idx4 << 2] = make_uint2(p0, p1);
  }
  for (int r = 0; r < 16; r++) {
    int idx = r * 256 + tid;
    int t = idx >> 7, d = idx & 127;
    so[t * 129 + d] = out[((size_t)((b * TT + t0 + t) * HH + h)) * DVv + d];
  }
  if (tid < DVv) snw[tid] = onw[tid];
  __syncthreads();

  {
    int t = tid >> 3, l8 = tid & 7;
    float ss = 0.f;
    for (int j = 0; j < 16; j++) { float x = so[t * 129 + l8 + (j << 3)]; ss += x * x; }
    ss += __shfl_down(ss, 4, 8);
    ss += __shfl_down(ss, 2, 8);
    ss += __shfl_down(ss, 1, 8);
    if (l8 == 0) {
      float rms = rsqrtf(ss * (1.f / 128.f) + 1e-5f);
      float gv = graw[(size_t)((b * TT + t0 + t) * HH + h)];
      float sig = 1.f / (1.f + expf(-gv));
      smul[t] = rms * gv * sig;
    }
  }
  __syncthreads();
  for (int r = 0; r < 16; r++) {
    int idx = r * 256 + tid;
    int t = idx >> 7, d = idx & 127;
    so[t * 129 + d] *= smul[t] * snw[d];
  }
  __syncthreads();

  {
    int ttile = tid >> 5;               // 4 tokens each
    int dt = tid & 31;                  // 4 output dims each
    int tb = ttile << 2;
    int d0 = dt << 2;
    float acc[4][4];
#pragma unroll
    for (int a = 0; a < 4; a++)
#pragma unroll
      for (int e = 0; e < 4; e++) acc[a][e] = 0.f;
    for (int vv = 0; vv < DVv; vv++) {
      uint2 u = *(const uint2*)&sP[vv * DKk + d0];
      float p0 = __uint_as_float(u.x << 16);
      float p1 = __uint_as_float(u.x & 0xffff0000u);
      float p2 = __uint_as_float(u.y << 16);
      float p3 = __uint_as_float(u.y & 0xffff0000u);
#pragma unroll
      for (int a = 0; a < 4; a++) {
        float ov = so[(tb + a) * 129 + vv];
        acc[a][0] += ov * p0; acc[a][1] += ov * p1; acc[a][2] += ov * p2; acc[a][3] += ov * p3;
      }
    }
#pragma unroll
    for (int a = 0; a < 4; a++) {
      size_t go = ((size_t)((b * TT + t0 + tb + a) * HH + h)) * DKk + d0;
      float4 r; r.x = acc[a][0]; r.y = acc[a][1]; r.z = acc[a][2]; r.w = acc[a][3];
      *(float4*)(out + go) = r;
    }
  }
}

// ---------------------------------------------------------------------------
extern "C" void kernel_launch(void* const* d_in, const int* in_sizes, int n_in,
                              void* d_out, int out_size, void* d_ws, size_t ws_size,
                              hipStream_t stream) {
  (void)in_sizes; (void)n_in; (void)out_size; (void)ws_size;
  const float* hab = (const float*)d_in[0];
  const float* hg  = (const float*)d_in[1];
  const float* q   = (const float*)d_in[2];
  const float* k   = (const float*)d_in[3];
  const float* v   = (const float*)d_in[4];
  const float* Wb  = (const float*)d_in[5];
  const float* Wg  = (const float*)d_in[6];
  const float* onw = (const float*)d_in[7];
  const float* opw = (const float*)d_in[8];
  float* out = (float*)d_out;

  // ws layout (bytes): beta 512K | graw 512K | qn 32M | kn 32M | T 16M | attn 16M
  char* ws = (char*)d_ws;
  float* beta          = (float*)(ws);
  float* graw          = (float*)(ws + 524288);
  unsigned short* qn   = (unsigned short*)(ws + 1048576);
  unsigned short* kn   = (unsigned short*)(ws + 34603008);
  unsigned short* Tg   = (unsigned short*)(ws + 68157440);
  unsigned short* Ag   = (unsigned short*)(ws + 84934656);

  hipLaunchKernelGGL(k1_beta_g, dim3(BB * TT), dim3(256), 0, stream,
                     hab, hg, Wb, Wg, beta, graw);
  hipLaunchKernelGGL(k2_l2norm, dim3(BB * TT * HH / 8), dim3(256), 0, stream,
                     q, k, qn, kn);
  hipLaunchKernelGGL(k3_chunk, dim3(BB * HH * NN), dim3(256), 0, stream,
                     qn, kn, beta, Tg, Ag);
  hipLaunchKernelGGL(k4_scan, dim3(BB * HH * GG), dim3(256), 0, stream,
                     qn, kn, v, beta, Tg, Ag, out);
  hipLaunchKernelGGL(k5_out, dim3(BB * (TT / 32) * HH), dim3(256), 0, stream,
                     graw, onw, opw, out);
}

// Round 2
// 1121.906 us; speedup vs baseline: 1.7029x; 1.7029x over previous
//
#include <hip/hip_runtime.h>
#include <hip/hip_bf16.h>

// Problem constants (DeltaNet_6614249636545)
#define BB 2
#define TT 4096
#define HH 16
#define DKk 128
#define DVv 128
#define HIDD 2048
#define CC 64
#define NN 64          // TT / CC
#define GG 8           // dv column groups in scan kernel
#define QSCALE 0.08838834764831845f  // 128^-0.5

static __device__ __forceinline__ unsigned short f2bf(float f) {
  unsigned u = __float_as_uint(f);
  u += 0x7fffu + ((u >> 16) & 1u);   // round-to-nearest-even
  return (unsigned short)(u >> 16);
}
static __device__ __forceinline__ float bf2f(unsigned short s) {
  return __uint_as_float(((unsigned)s) << 16);
}

// ---------------------------------------------------------------------------
// K1: beta = sigmoid(hidden_ab @ Wb), graw = hidden_g @ Wg   (one block/token)
// ---------------------------------------------------------------------------
__global__ __launch_bounds__(256) void k1_beta_g(
    const float* __restrict__ hab, const float* __restrict__ hg,
    const float* __restrict__ Wb, const float* __restrict__ Wg,
    float* __restrict__ beta, float* __restrict__ graw) {
  int token = blockIdx.x;
  int tid = threadIdx.x;
  const float* pa = hab + (size_t)token * HIDD;
  const float* pg = hg + (size_t)token * HIDD;
  float accb[HH], accg[HH];
#pragma unroll
  for (int h = 0; h < HH; h++) { accb[h] = 0.f; accg[h] = 0.f; }
  for (int r = 0; r < 2; r++) {
    int i = r * 1024 + tid * 4;
    float4 xa = *(const float4*)(pa + i);
    float4 xg = *(const float4*)(pg + i);
    float av[4] = {xa.x, xa.y, xa.z, xa.w};
    float gv[4] = {xg.x, xg.y, xg.z, xg.w};
#pragma unroll
    for (int s = 0; s < 4; s++) {
      const float* wb = Wb + (size_t)(i + s) * HH;
      const float* wg = Wg + (size_t)(i + s) * HH;
#pragma unroll
      for (int h = 0; h < HH; h++) { accb[h] += av[s] * wb[h]; accg[h] += gv[s] * wg[h]; }
    }
  }
  __shared__ float red[32][257];
#pragma unroll
  for (int h = 0; h < HH; h++) { red[h][tid] = accb[h]; red[HH + h][tid] = accg[h]; }
  __syncthreads();
  int row = tid >> 3, l8 = tid & 7;
  float p = 0.f;
  for (int j = 0; j < 32; j++) p += red[row][l8 + 8 * j];
  p += __shfl_down(p, 4, 8);
  p += __shfl_down(p, 2, 8);
  p += __shfl_down(p, 1, 8);
  if (l8 == 0) {
    if (row < HH) beta[(size_t)token * HH + row] = 1.f / (1.f + expf(-p));
    else          graw[(size_t)token * HH + (row - HH)] = p;
  }
}

// ---------------------------------------------------------------------------
// K2: l2norm(q)*scale -> qn (bf16), l2norm(k) -> kn (bf16)
// ---------------------------------------------------------------------------
__global__ __launch_bounds__(256) void k2_l2norm(
    const float* __restrict__ q, const float* __restrict__ k,
    unsigned short* __restrict__ qn, unsigned short* __restrict__ kn) {
  int lane = threadIdx.x & 63, wave = threadIdx.x >> 6;
  for (int u = 0; u < 2; u++) {
    int vec = blockIdx.x * 8 + wave * 2 + u;
    size_t off = (size_t)vec * 64 + lane;
    float2 q2 = ((const float2*)q)[off];
    float2 k2 = ((const float2*)k)[off];
    float sq = q2.x * q2.x + q2.y * q2.y;
    float sk = k2.x * k2.x + k2.y * k2.y;
#pragma unroll
    for (int m = 32; m; m >>= 1) { sq += __shfl_xor(sq, m); sk += __shfl_xor(sk, m); }
    float rq = rsqrtf(sq + 1e-6f) * QSCALE;
    float rk = rsqrtf(sk + 1e-6f);
    unsigned pq = (unsigned)f2bf(q2.x * rq) | ((unsigned)f2bf(q2.y * rq) << 16);
    unsigned pk = (unsigned)f2bf(k2.x * rk) | ((unsigned)f2bf(k2.y * rk) << 16);
    ((unsigned*)qn)[off] = pq;
    ((unsigned*)kn)[off] = pk;
  }
}

// ---------------------------------------------------------------------------
// K3: per chunk (b,h,n): attn = tril(q k^T) -> global,
//     A = tril(k_beta k^T,-1);  T = (I+A)^{-1} -> global (bf16)
// ---------------------------------------------------------------------------
__global__ __launch_bounds__(256) void k3_chunk(
    const unsigned short* __restrict__ qn, const unsigned short* __restrict__ kn,
    const float* __restrict__ beta,
    unsigned short* __restrict__ Tg, unsigned short* __restrict__ Ag) {
  int cid = blockIdx.x;
  int n = cid & (NN - 1);
  int bh = cid / NN;
  int h = bh & (HH - 1);
  int b = bh / HH;
  int tid = threadIdx.x;

  __shared__ __align__(16) unsigned short sk[CC * 129];   // 16512 B
  __shared__ __align__(16) unsigned short sq[CC * 129];   // 16512 B
  __shared__ __align__(16) unsigned short sA[CC * 65];    //  8320 B
  __shared__ __align__(16) float sM[CC * 65];             // 16640 B
  __shared__ float sb[CC];

  int t0 = n * CC;
  for (int r = 0; r < 8; r++) {
    int idx4 = r * 256 + tid;            // 2048 quads
    int c = idx4 >> 5;
    int d4 = (idx4 & 31) << 2;
    size_t g = ((size_t)((b * TT + t0 + c) * HH + h)) * DKk + d4;
    ushort4 vk = *(const ushort4*)(kn + g);
    ushort4 vq = *(const ushort4*)(qn + g);
    int o = c * 129 + d4;
    sk[o] = vk.x; sk[o + 1] = vk.y; sk[o + 2] = vk.z; sk[o + 3] = vk.w;
    sq[o] = vq.x; sq[o + 1] = vq.y; sq[o + 2] = vq.z; sq[o + 3] = vq.w;
  }
  if (tid < CC) sb[tid] = beta[(size_t)((b * TT + t0 + tid) * HH + h)];
  for (int r = 0; r < 16; r++) {
    int idx = r * 256 + tid;
    int i = idx >> 6, j = idx & 63;
    sM[i * 65 + j] = (i == j) ? 1.f : 0.f;
  }
  __syncthreads();

  int iq = tid >> 4, jqt = tid & 15;
  int i0 = iq << 2, j0 = jqt << 2;
  size_t abase = (size_t)cid * (CC * CC);

  // attn = tril(q k^T, 0) -> global bf16 (upper zeros)
  {
    float acc[4][4];
#pragma unroll
    for (int a = 0; a < 4; a++)
#pragma unroll
      for (int e = 0; e < 4; e++) acc[a][e] = 0.f;
    if (j0 <= i0 + 3) {
      for (int d = 0; d < DKk; d++) {
        float qv[4], kv[4];
#pragma unroll
        for (int a = 0; a < 4; a++) qv[a] = bf2f(sq[(i0 + a) * 129 + d]);
#pragma unroll
        for (int e = 0; e < 4; e++) kv[e] = bf2f(sk[(j0 + e) * 129 + d]);
#pragma unroll
        for (int a = 0; a < 4; a++)
#pragma unroll
          for (int e = 0; e < 4; e++) acc[a][e] += qv[a] * kv[e];
      }
    }
#pragma unroll
    for (int a = 0; a < 4; a++)
#pragma unroll
      for (int e = 0; e < 4; e++) {
        int i = i0 + a, j = j0 + e;
        Ag[abase + i * CC + j] = f2bf((j <= i) ? acc[a][e] : 0.f);
      }
  }
  // A = tril(k_beta k^T, -1) -> LDS bf16
  {
    float acc[4][4];
#pragma unroll
    for (int a = 0; a < 4; a++)
#pragma unroll
      for (int e = 0; e < 4; e++) acc[a][e] = 0.f;
    if (j0 <= i0 + 3) {
      for (int d = 0; d < DKk; d++) {
        float ki[4], kj[4];
#pragma unroll
        for (int a = 0; a < 4; a++) ki[a] = bf2f(sk[(i0 + a) * 129 + d]);
#pragma unroll
        for (int e = 0; e < 4; e++) kj[e] = bf2f(sk[(j0 + e) * 129 + d]);
#pragma unroll
        for (int a = 0; a < 4; a++)
#pragma unroll
          for (int e = 0; e < 4; e++) acc[a][e] += ki[a] * kj[e];
      }
    }
#pragma unroll
    for (int a = 0; a < 4; a++)
#pragma unroll
      for (int e = 0; e < 4; e++) {
        int i = i0 + a, j = j0 + e;
        sA[i * 65 + j] = f2bf((j < i) ? sb[i] * acc[a][e] : 0.f);
      }
  }
  __syncthreads();

  // T = (I+A)^{-1}: lane j owns column j
  if (tid < CC) {
    int j = tid;
    for (int i = j + 1; i < CC; i++) {
      float s = bf2f(sA[i * 65 + j]);
      for (int kk = j + 1; kk < i; kk++)
        s += bf2f(sA[i * 65 + kk]) * sM[kk * 65 + j];
      sM[i * 65 + j] = -s;
    }
  }
  __syncthreads();

  for (int r = 0; r < 16; r++) {
    int idx = r * 256 + tid;
    int i = idx >> 6, j = idx & 63;
    Tg[abase + idx] = f2bf(sM[i * 65 + j]);
  }
}

// ---------------------------------------------------------------------------
// K4 (MFMA): sequential chunk scan. block = (b,h,jg), 16 DV cols, 4 waves.
//   x  = beta_c * (v - k @ S)  ->  vi = T @ x  ->  o = q@S + attn@vi
//   S += k^T @ vi  (fp32 MFMA accumulators in registers, bf16 copy in LDS)
// blockIdx = jg*32 + bh so the 8 DV-siblings of one (b,h) share an XCD (L2 dedup)
// ---------------------------------------------------------------------------
typedef short bf8 __attribute__((ext_vector_type(8)));
typedef float f4 __attribute__((ext_vector_type(4)));

__global__ __launch_bounds__(256) void k4_scan(
    const unsigned short* __restrict__ qn, const unsigned short* __restrict__ kn,
    const float* __restrict__ v, const float* __restrict__ beta,
    const unsigned short* __restrict__ Tg, const unsigned short* __restrict__ Ag,
    float* __restrict__ o) {
  int bi = blockIdx.x;                 // jg*32 + bh
  int jg = bi >> 5;
  int bh = bi & 31;
  int h = bh & (HH - 1);
  int b = bh >> 4;
  int tid = threadIdx.x;
  int j0 = jg * 16;
  int w = tid >> 6;
  int lane = tid & 63;
  int n16 = lane & 15;
  int qd = lane >> 4;
  int r0 = w * 16;                     // chunk-row tile of this wave
  int dkbase = w * 32;                 // S dk-rows owned by this wave

  __shared__ __align__(16) unsigned short sk[CC * 136];   // 17408 B [c][dk]
  __shared__ __align__(16) unsigned short sq[CC * 136];   // 17408 B
  __shared__ __align__(16) unsigned short sT[CC * 72];    //  9216 B [i][j]
  __shared__ __align__(16) unsigned short sA[CC * 72];    //  9216 B
  __shared__ __align__(16) unsigned short sSb[16 * 136];  //  4352 B S^T: [col][dk]
  __shared__ __align__(16) unsigned short sxT[16 * 72];   //  2304 B x^T: [col][c]
  __shared__ __align__(16) unsigned short svT[16 * 72];   //  2304 B vi^T
  __shared__ float sb[CC];                                //   256 B (total 62464)

  f4 S0 = {0.f, 0.f, 0.f, 0.f}, S1 = {0.f, 0.f, 0.f, 0.f};
  for (int i = tid; i < 16 * 136; i += 256) sSb[i] = 0;

  int bhBase = (b * HH + h) * NN;

  uint4 pk[4], pq[4], pt[2], pa[2];
  float4 pv;
  float pb = 0.f;

  // prefetch chunk 0
  {
#pragma unroll
    for (int p = 0; p < 4; p++) {
      int id = p * 256 + tid, row = id >> 4, c8 = (id & 15) << 3;
      size_t g = ((size_t)((b * TT + row) * HH + h)) * DKk + c8;
      pk[p] = *(const uint4*)(kn + g);
      pq[p] = *(const uint4*)(qn + g);
    }
    size_t cb = (size_t)bhBase * (CC * CC);
#pragma unroll
    for (int p = 0; p < 2; p++) {
      int id = p * 256 + tid, row = id >> 3, c8 = (id & 7) << 3;
      pt[p] = *(const uint4*)(Tg + cb + row * CC + c8);
      pa[p] = *(const uint4*)(Ag + cb + row * CC + c8);
    }
    {
      int c = tid >> 2, c4 = (tid & 3) << 2;
      pv = *(const float4*)(v + ((size_t)((b * TT + c) * HH + h)) * DVv + j0 + c4);
    }
    if (tid < CC) pb = beta[(size_t)((b * TT + tid) * HH + h)];
  }

  for (int n = 0; n < NN; n++) {
    int t0 = n * CC;
    // ---- stage regs -> LDS
#pragma unroll
    for (int p = 0; p < 4; p++) {
      int id = p * 256 + tid, row = id >> 4, c8 = (id & 15) << 3;
      *(uint4*)&sk[row * 136 + c8] = pk[p];
      *(uint4*)&sq[row * 136 + c8] = pq[p];
    }
#pragma unroll
    for (int p = 0; p < 2; p++) {
      int id = p * 256 + tid, row = id >> 3, c8 = (id & 7) << 3;
      *(uint4*)&sT[row * 72 + c8] = pt[p];
      *(uint4*)&sA[row * 72 + c8] = pa[p];
    }
    {
      int c = tid >> 2, c4 = (tid & 3) << 2;
      sxT[(c4 + 0) * 72 + c] = f2bf(pv.x);
      sxT[(c4 + 1) * 72 + c] = f2bf(pv.y);
      sxT[(c4 + 2) * 72 + c] = f2bf(pv.z);
      sxT[(c4 + 3) * 72 + c] = f2bf(pv.w);
    }
    if (tid < CC) sb[tid] = pb;
    __syncthreads();   // B1: staging visible

    // ---- prefetch next chunk into regs (latency hidden behind compute)
    if (n + 1 < NN) {
      int t0n = t0 + CC;
#pragma unroll
      for (int p = 0; p < 4; p++) {
        int id = p * 256 + tid, row = id >> 4, c8 = (id & 15) << 3;
        size_t g = ((size_t)((b * TT + t0n + row) * HH + h)) * DKk + c8;
        pk[p] = *(const uint4*)(kn + g);
        pq[p] = *(const uint4*)(qn + g);
      }
      size_t cb = (size_t)(bhBase + n + 1) * (CC * CC);
#pragma unroll
      for (int p = 0; p < 2; p++) {
        int id = p * 256 + tid, row = id >> 3, c8 = (id & 7) << 3;
        pt[p] = *(const uint4*)(Tg + cb + row * CC + c8);
        pa[p] = *(const uint4*)(Ag + cb + row * CC + c8);
      }
      {
        int c = tid >> 2, c4 = (tid & 3) << 2;
        pv = *(const float4*)(v + ((size_t)((b * TT + t0n + c) * HH + h)) * DVv + j0 + c4);
      }
      if (tid < CC) pb = beta[(size_t)((b * TT + t0n + tid) * HH + h)];
    }

    // ---- x^T = beta * (v - k@S)^T   (in-place in sxT)
    {
      f4 acc = {0.f, 0.f, 0.f, 0.f};
#pragma unroll
      for (int s = 0; s < 4; s++) {
        bf8 a = *(const bf8*)&sk[(r0 + n16) * 136 + s * 32 + qd * 8];
        bf8 bb = *(const bf8*)&sSb[n16 * 136 + s * 32 + qd * 8];
        acc = __builtin_amdgcn_mfma_f32_16x16x32_bf16(a, bb, acc, 0, 0, 0);
      }
#pragma unroll
      for (int r = 0; r < 4; r++) {
        int c = r0 + qd * 4 + r;
        float vval = bf2f(sxT[n16 * 72 + c]);
        sxT[n16 * 72 + c] = f2bf(sb[c] * (vval - acc[r]));
      }
    }
    __syncthreads();   // B2

    // ---- vi = T @ x -> svT (bf16, transposed)
    {
      f4 acc = {0.f, 0.f, 0.f, 0.f};
#pragma unroll
      for (int s = 0; s < 2; s++) {
        bf8 a = *(const bf8*)&sT[(r0 + n16) * 72 + s * 32 + qd * 8];
        bf8 bb = *(const bf8*)&sxT[n16 * 72 + s * 32 + qd * 8];
        acc = __builtin_amdgcn_mfma_f32_16x16x32_bf16(a, bb, acc, 0, 0, 0);
      }
#pragma unroll
      for (int r = 0; r < 4; r++) {
        int c = r0 + qd * 4 + r;
        svT[n16 * 72 + c] = f2bf(acc[r]);
      }
    }
    __syncthreads();   // B3

    // ---- o = q@S_old + attn@vi -> global
    {
      f4 acc = {0.f, 0.f, 0.f, 0.f};
#pragma unroll
      for (int s = 0; s < 4; s++) {
        bf8 a = *(const bf8*)&sq[(r0 + n16) * 136 + s * 32 + qd * 8];
        bf8 bb = *(const bf8*)&sSb[n16 * 136 + s * 32 + qd * 8];
        acc = __builtin_amdgcn_mfma_f32_16x16x32_bf16(a, bb, acc, 0, 0, 0);
      }
#pragma unroll
      for (int s = 0; s < 2; s++) {
        bf8 a = *(const bf8*)&sA[(r0 + n16) * 72 + s * 32 + qd * 8];
        bf8 bb = *(const bf8*)&svT[n16 * 72 + s * 32 + qd * 8];
        acc = __builtin_amdgcn_mfma_f32_16x16x32_bf16(a, bb, acc, 0, 0, 0);
      }
#pragma unroll
      for (int r = 0; r < 4; r++) {
        int c = r0 + qd * 4 + r;
        o[((size_t)((b * TT + t0 + c) * HH + h)) * DVv + j0 + n16] = acc[r];
      }
    }

    // ---- S += k^T @ vi   (register accumulators, per-wave dk rows)
    {
#pragma unroll
      for (int t = 0; t < 2; t++) {
        int dkt = dkbase + t * 16;
        f4 acc = t ? S1 : S0;
#pragma unroll
        for (int s = 0; s < 2; s++) {
          bf8 a;
#pragma unroll
          for (int j = 0; j < 8; j++)
            a[j] = (short)sk[(s * 32 + qd * 8 + j) * 136 + dkt + n16];
          bf8 bb = *(const bf8*)&svT[n16 * 72 + s * 32 + qd * 8];
          acc = __builtin_amdgcn_mfma_f32_16x16x32_bf16(a, bb, acc, 0, 0, 0);
        }
        if (t) S1 = acc; else S0 = acc;
      }
    }
    __syncthreads();   // B4: all reads of sSb/sk/sq/sxT/svT done

    // ---- write new S (bf16) to sSb
#pragma unroll
    for (int r = 0; r < 4; r++) {
      sSb[n16 * 136 + dkbase + qd * 4 + r] = f2bf(S0[r]);
      sSb[n16 * 136 + dkbase + 16 + qd * 4 + r] = f2bf(S1[r]);
    }
  }
}

// ---------------------------------------------------------------------------
// K5: in-place on d_out: RMSNorm(o)*o_norm_w * swish(g), then per-head
//     projection out[t, h*128+d] = sum_v o~[v] * P[h,v,d].
// ---------------------------------------------------------------------------
__global__ __launch_bounds__(256) void k5_out(
    const float* __restrict__ graw, const float* __restrict__ onw,
    const float* __restrict__ opw, float* __restrict__ out) {
  int bi = blockIdx.x;                  // B*(T/32)*H = 4096
  int h = bi & (HH - 1);
  int tt = (bi >> 4) & 127;
  int b = bi >> 11;
  int t0 = tt * 32;
  int tid = threadIdx.x;

  __shared__ __align__(16) unsigned short sP[DVv * DKk];  // 32768 B (bf16)
  __shared__ __align__(16) float so[32 * 129];            // 16512 B
  __shared__ float smul[32];
  __shared__ float snw[DVv];

  const float* P = opw + (size_t)h * DVv * DKk;
  for (int r = 0; r < 16; r++) {
    int idx4 = r * 256 + tid;           // 4096 quads
    float4 pvv = *(const float4*)(P + ((size_t)idx4 << 2));
    unsigned p0 = (unsigned)f2bf(pvv.x) | ((unsigned)f2bf(pvv.y) << 16);
    unsigned p1 = (unsigned)f2bf(pvv.z) | ((unsigned)f2bf(pvv.w) << 16);
    *(uint2*)&sP[idx4 << 2] = make_uint2(p0, p1);
  }
  for (int r = 0; r < 16; r++) {
    int idx = r * 256 + tid;
    int t = idx >> 7, d = idx & 127;
    so[t * 129 + d] = out[((size_t)((b * TT + t0 + t) * HH + h)) * DVv + d];
  }
  if (tid < DVv) snw[tid] = onw[tid];
  __syncthreads();

  {
    int t = tid >> 3, l8 = tid & 7;
    float ss = 0.f;
    for (int j = 0; j < 16; j++) { float x = so[t * 129 + l8 + (j << 3)]; ss += x * x; }
    ss += __shfl_down(ss, 4, 8);
    ss += __shfl_down(ss, 2, 8);
    ss += __shfl_down(ss, 1, 8);
    if (l8 == 0) {
      float rms = rsqrtf(ss * (1.f / 128.f) + 1e-5f);
      float gv = graw[(size_t)((b * TT + t0 + t) * HH + h)];
      float sig = 1.f / (1.f + expf(-gv));
      smul[t] = rms * gv * sig;
    }
  }
  __syncthreads();
  for (int r = 0; r < 16; r++) {
    int idx = r * 256 + tid;
    int t = idx >> 7, d = idx & 127;
    so[t * 129 + d] *= smul[t] * snw[d];
  }
  __syncthreads();

  {
    int ttile = tid >> 5;               // 4 tokens each
    int dt = tid & 31;                  // 4 output dims each
    int tb = ttile << 2;
    int d0 = dt << 2;
    float acc[4][4];
#pragma unroll
    for (int a = 0; a < 4; a++)
#pragma unroll
      for (int e = 0; e < 4; e++) acc[a][e] = 0.f;
    for (int vv = 0; vv < DVv; vv++) {
      uint2 u = *(const uint2*)&sP[vv * DKk + d0];
      float p0 = __uint_as_float(u.x << 16);
      float p1 = __uint_as_float(u.x & 0xffff0000u);
      float p2 = __uint_as_float(u.y << 16);
      float p3 = __uint_as_float(u.y & 0xffff0000u);
#pragma unroll
      for (int a = 0; a < 4; a++) {
        float ov = so[(tb + a) * 129 + vv];
        acc[a][0] += ov * p0; acc[a][1] += ov * p1; acc[a][2] += ov * p2; acc[a][3] += ov * p3;
      }
    }
#pragma unroll
    for (int a = 0; a < 4; a++) {
      size_t go = ((size_t)((b * TT + t0 + tb + a) * HH + h)) * DKk + d0;
      float4 r; r.x = acc[a][0]; r.y = acc[a][1]; r.z = acc[a][2]; r.w = acc[a][3];
      *(float4*)(out + go) = r;
    }
  }
}

// ---------------------------------------------------------------------------
extern "C" void kernel_launch(void* const* d_in, const int* in_sizes, int n_in,
                              void* d_out, int out_size, void* d_ws, size_t ws_size,
                              hipStream_t stream) {
  (void)in_sizes; (void)n_in; (void)out_size; (void)ws_size;
  const float* hab = (const float*)d_in[0];
  const float* hg  = (const float*)d_in[1];
  const float* q   = (const float*)d_in[2];
  const float* k   = (const float*)d_in[3];
  const float* v   = (const float*)d_in[4];
  const float* Wb  = (const float*)d_in[5];
  const float* Wg  = (const float*)d_in[6];
  const float* onw = (const float*)d_in[7];
  const float* opw = (const float*)d_in[8];
  float* out = (float*)d_out;

  // ws layout (bytes): beta 512K | graw 512K | qn 32M | kn 32M | T 16M | attn 16M
  char* ws = (char*)d_ws;
  float* beta          = (float*)(ws);
  float* graw          = (float*)(ws + 524288);
  unsigned short* qn   = (unsigned short*)(ws + 1048576);
  unsigned short* kn   = (unsigned short*)(ws + 34603008);
  unsigned short* Tg   = (unsigned short*)(ws + 68157440);
  unsigned short* Ag   = (unsigned short*)(ws + 84934656);

  hipLaunchKernelGGL(k1_beta_g, dim3(BB * TT), dim3(256), 0, stream,
                     hab, hg, Wb, Wg, beta, graw);
  hipLaunchKernelGGL(k2_l2norm, dim3(BB * TT * HH / 8), dim3(256), 0, stream,
                     q, k, qn, kn);
  hipLaunchKernelGGL(k3_chunk, dim3(BB * HH * NN), dim3(256), 0, stream,
                     qn, kn, beta, Tg, Ag);
  hipLaunchKernelGGL(k4_scan, dim3(BB * HH * GG), dim3(256), 0, stream,
                     qn, kn, v, beta, Tg, Ag, out);
  hipLaunchKernelGGL(k5_out, dim3(BB * (TT / 32) * HH), dim3(256), 0, stream,
                     graw, onw, opw, out);
}

// Round 3
// 870.314 us; speedup vs baseline: 2.1952x; 1.2891x over previous
//
#include <hip/hip_runtime.h>
#include <hip/hip_bf16.h>

// Problem constants (DeltaNet_6614249636545)
#define BB 2
#define TT 4096
#define HH 16
#define DKk 128
#define DVv 128
#define HIDD 2048
#define CC 64
#define NN 64          // TT / CC
#define GG 8           // dv column groups in scan kernel
#define QSCALE 0.08838834764831845f  // 128^-0.5

static __device__ __forceinline__ unsigned short f2bf(float f) {
  unsigned u = __float_as_uint(f);
  u += 0x7fffu + ((u >> 16) & 1u);   // round-to-nearest-even
  return (unsigned short)(u >> 16);
}
static __device__ __forceinline__ float bf2f(unsigned short s) {
  return __uint_as_float(((unsigned)s) << 16);
}

typedef short bf8 __attribute__((ext_vector_type(8)));
typedef float f4 __attribute__((ext_vector_type(4)));

// ---------------------------------------------------------------------------
// K1: beta = sigmoid(hidden_ab @ Wb), graw = hidden_g @ Wg   (one block/token)
// ---------------------------------------------------------------------------
__global__ __launch_bounds__(256) void k1_beta_g(
    const float* __restrict__ hab, const float* __restrict__ hg,
    const float* __restrict__ Wb, const float* __restrict__ Wg,
    float* __restrict__ beta, float* __restrict__ graw) {
  int token = blockIdx.x;
  int tid = threadIdx.x;
  const float* pa = hab + (size_t)token * HIDD;
  const float* pg = hg + (size_t)token * HIDD;
  float accb[HH], accg[HH];
#pragma unroll
  for (int h = 0; h < HH; h++) { accb[h] = 0.f; accg[h] = 0.f; }
  for (int r = 0; r < 2; r++) {
    int i = r * 1024 + tid * 4;
    float4 xa = *(const float4*)(pa + i);
    float4 xg = *(const float4*)(pg + i);
    float av[4] = {xa.x, xa.y, xa.z, xa.w};
    float gv[4] = {xg.x, xg.y, xg.z, xg.w};
#pragma unroll
    for (int s = 0; s < 4; s++) {
      const float* wb = Wb + (size_t)(i + s) * HH;
      const float* wg = Wg + (size_t)(i + s) * HH;
#pragma unroll
      for (int h = 0; h < HH; h++) { accb[h] += av[s] * wb[h]; accg[h] += gv[s] * wg[h]; }
    }
  }
  __shared__ float red[32][257];
#pragma unroll
  for (int h = 0; h < HH; h++) { red[h][tid] = accb[h]; red[HH + h][tid] = accg[h]; }
  __syncthreads();
  int row = tid >> 3, l8 = tid & 7;
  float p = 0.f;
  for (int j = 0; j < 32; j++) p += red[row][l8 + 8 * j];
  p += __shfl_down(p, 4, 8);
  p += __shfl_down(p, 2, 8);
  p += __shfl_down(p, 1, 8);
  if (l8 == 0) {
    if (row < HH) beta[(size_t)token * HH + row] = 1.f / (1.f + expf(-p));
    else          graw[(size_t)token * HH + (row - HH)] = p;
  }
}

// ---------------------------------------------------------------------------
// K2: l2norm(q)*scale -> qn (bf16), l2norm(k) -> kn (bf16)
// ---------------------------------------------------------------------------
__global__ __launch_bounds__(256) void k2_l2norm(
    const float* __restrict__ q, const float* __restrict__ k,
    unsigned short* __restrict__ qn, unsigned short* __restrict__ kn) {
  int lane = threadIdx.x & 63, wave = threadIdx.x >> 6;
  for (int u = 0; u < 2; u++) {
    int vec = blockIdx.x * 8 + wave * 2 + u;
    size_t off = (size_t)vec * 64 + lane;
    float2 q2 = ((const float2*)q)[off];
    float2 k2 = ((const float2*)k)[off];
    float sq = q2.x * q2.x + q2.y * q2.y;
    float sk = k2.x * k2.x + k2.y * k2.y;
#pragma unroll
    for (int m = 32; m; m >>= 1) { sq += __shfl_xor(sq, m); sk += __shfl_xor(sk, m); }
    float rq = rsqrtf(sq + 1e-6f) * QSCALE;
    float rk = rsqrtf(sk + 1e-6f);
    unsigned pq = (unsigned)f2bf(q2.x * rq) | ((unsigned)f2bf(q2.y * rq) << 16);
    unsigned pk = (unsigned)f2bf(k2.x * rk) | ((unsigned)f2bf(k2.y * rk) << 16);
    ((unsigned*)qn)[off] = pq;
    ((unsigned*)kn)[off] = pk;
  }
}

// ---------------------------------------------------------------------------
// K3 (MFMA): per chunk: attn = tril(q k^T) -> Ag,
//   A = tril(k_beta k^T,-1), T = (I+A)^{-1} -> Tg via nilpotent doubling:
//   (I+A)^{-1} = (I+M)(I+M^2)(I+M^4)(I+M^8)(I+M^16)(I+M^32), M = -A (M^64=0).
//   T accumulated fp32 in registers; M powers bf16 in LDS (row + col major).
// 4 waves; wave w owns row band [16w,16w+16). LDS arena 46.3 KB -> 3 blk/CU.
// ---------------------------------------------------------------------------
#define SW 72          // stride (shorts) of 64x64 bf16 mats
#define O_M0R 0        // offsets in shorts
#define O_M0T 4608
#define O_M1R 9216
#define O_M1T 13824
#define O_TB  18432    // T^T (col-major shadow of T), bf16
#define ARENA_SH 23040

__global__ __launch_bounds__(256) void k3_chunk(
    const unsigned short* __restrict__ qn, const unsigned short* __restrict__ kn,
    const float* __restrict__ beta,
    unsigned short* __restrict__ Tg, unsigned short* __restrict__ Ag) {
  int cid = blockIdx.x;
  int n = cid & (NN - 1);
  int bh = cid / NN;
  int h = bh & (HH - 1);
  int b = bh / HH;
  int tid = threadIdx.x;
  int w = tid >> 6;
  int lane = tid & 63;
  int n16 = lane & 15;
  int qd = lane >> 4;
  int r0 = w * 16;

  __shared__ __align__(16) unsigned short arena[ARENA_SH];  // 46080 B
  __shared__ float sb[CC];
  unsigned short* sk = arena;           // [c][dk] stride 136, 8704 shorts
  unsigned short* sq = arena + 8704;    // aliased by M buffers after init

  int t0 = n * CC;
  // ---- stage k, q (bf16, stride 136), beta
#pragma unroll
  for (int p = 0; p < 4; p++) {
    int id = p * 256 + tid, row = id >> 4, c8 = (id & 15) << 3;
    size_t g = ((size_t)((b * TT + t0 + row) * HH + h)) * DKk + c8;
    *(uint4*)&sk[row * 136 + c8] = *(const uint4*)(kn + g);
    *(uint4*)&sq[row * 136 + c8] = *(const uint4*)(qn + g);
  }
  if (tid < CC) sb[tid] = beta[(size_t)((b * TT + t0 + tid) * HH + h)];
  __syncthreads();

  // ---- attn = q k^T and raw kk = k k^T   (MFMA, K=128)
  f4 at[4], mk[4];
#pragma unroll
  for (int ct = 0; ct < 4; ct++) { at[ct] = (f4){0,0,0,0}; mk[ct] = (f4){0,0,0,0}; }
#pragma unroll
  for (int s = 0; s < 4; s++) {
    bf8 aq = *(const bf8*)&sq[(r0 + n16) * 136 + s * 32 + qd * 8];
    bf8 ak = *(const bf8*)&sk[(r0 + n16) * 136 + s * 32 + qd * 8];
#pragma unroll
    for (int ct = 0; ct < 4; ct++) {
      bf8 bk = *(const bf8*)&sk[(ct * 16 + n16) * 136 + s * 32 + qd * 8];
      at[ct] = __builtin_amdgcn_mfma_f32_16x16x32_bf16(aq, bk, at[ct], 0, 0, 0);
      mk[ct] = __builtin_amdgcn_mfma_f32_16x16x32_bf16(ak, bk, mk[ct], 0, 0, 0);
    }
  }

  size_t abase = (size_t)cid * (CC * CC);
  // write attn (tril incl diag) to global; build Mp = -tril(beta_i*kk,-1), Tf = I+Mp
  f4 tf[4];
  float mpv[4][4];
#pragma unroll
  for (int ct = 0; ct < 4; ct++) {
#pragma unroll
    for (int r = 0; r < 4; r++) {
      int i = r0 + qd * 4 + r, j = ct * 16 + n16;
      Ag[abase + i * CC + j] = f2bf((j <= i) ? at[ct][r] : 0.f);
      float mp = (j < i) ? -sb[i] * mk[ct][r] : 0.f;
      mpv[ct][r] = mp;
      tf[ct][r] = (i == j) ? 1.f : mp;
    }
  }
  __syncthreads();   // reads of sk/sq done; arena can be re-purposed

  // write Mp (row + transposed) and Tb = T^T (bf16 shadow)
#pragma unroll
  for (int ct = 0; ct < 4; ct++) {
#pragma unroll
    for (int r = 0; r < 4; r++) {
      int i = r0 + qd * 4 + r, j = ct * 16 + n16;
      unsigned short hm = f2bf(mpv[ct][r]);
      arena[O_M0R + i * SW + j] = hm;
      arena[O_M0T + j * SW + i] = hm;
      arena[O_TB + j * SW + i] = f2bf(tf[ct][r]);
    }
  }
  __syncthreads();

  // ---- 5 doubling iterations
  int p = 0;
  for (int it = 1; it <= 5; it++) {
    int mrp = p ? O_M1R : O_M0R, mtp = p ? O_M1T : O_M0T;
    int mrn = p ? O_M0R : O_M1R, mtn = p ? O_M0T : O_M1T;
    // phase A: N = Mp^2 -> Mp[1-p]
    f4 nr[4];
#pragma unroll
    for (int ct = 0; ct < 4; ct++) nr[ct] = (f4){0,0,0,0};
#pragma unroll
    for (int s = 0; s < 2; s++) {
      bf8 a = *(const bf8*)&arena[mrp + (r0 + n16) * SW + s * 32 + qd * 8];
#pragma unroll
      for (int ct = 0; ct < 4; ct++) {
        bf8 bb = *(const bf8*)&arena[mtp + (ct * 16 + n16) * SW + s * 32 + qd * 8];
        nr[ct] = __builtin_amdgcn_mfma_f32_16x16x32_bf16(a, bb, nr[ct], 0, 0, 0);
      }
    }
#pragma unroll
    for (int ct = 0; ct < 4; ct++) {
#pragma unroll
      for (int r = 0; r < 4; r++) {
        int i = r0 + qd * 4 + r, j = ct * 16 + n16;
        unsigned short hm = f2bf(nr[ct][r]);
        arena[mrn + i * SW + j] = hm;
        arena[mtn + j * SW + i] = hm;
      }
    }
    __syncthreads();  // B1: N visible; reads of Mp[p] complete

    // phase B: Tf += N · T   (N = Mp[1-p], T from bf16 shadow Tb)
#pragma unroll
    for (int s = 0; s < 2; s++) {
      bf8 a = *(const bf8*)&arena[mrn + (r0 + n16) * SW + s * 32 + qd * 8];
#pragma unroll
      for (int ct = 0; ct < 4; ct++) {
        bf8 bb = *(const bf8*)&arena[O_TB + (ct * 16 + n16) * SW + s * 32 + qd * 8];
        tf[ct] = __builtin_amdgcn_mfma_f32_16x16x32_bf16(a, bb, tf[ct], 0, 0, 0);
      }
    }
    __syncthreads();  // B2: reads of Tb complete

    if (it < 5) {
      // phase C: refresh Tb from fp32 Tf (next iter's B1 makes it visible)
#pragma unroll
      for (int ct = 0; ct < 4; ct++) {
#pragma unroll
        for (int r = 0; r < 4; r++) {
          int i = r0 + qd * 4 + r, j = ct * 16 + n16;
          arena[O_TB + j * SW + i] = f2bf(tf[ct][r]);
        }
      }
    }
    p = 1 - p;
  }

  // ---- write T (row-major bf16) to global
#pragma unroll
  for (int ct = 0; ct < 4; ct++) {
#pragma unroll
    for (int r = 0; r < 4; r++) {
      int i = r0 + qd * 4 + r, j = ct * 16 + n16;
      Tg[abase + i * CC + j] = f2bf(tf[ct][r]);
    }
  }
}

// ---------------------------------------------------------------------------
// K4 (MFMA): sequential chunk scan. block = (b,h,jg), 16 DV cols, 4 waves.
// ---------------------------------------------------------------------------
__global__ __launch_bounds__(256) void k4_scan(
    const unsigned short* __restrict__ qn, const unsigned short* __restrict__ kn,
    const float* __restrict__ v, const float* __restrict__ beta,
    const unsigned short* __restrict__ Tg, const unsigned short* __restrict__ Ag,
    float* __restrict__ o) {
  int bi = blockIdx.x;                 // jg*32 + bh
  int jg = bi >> 5;
  int bh = bi & 31;
  int h = bh & (HH - 1);
  int b = bh >> 4;
  int tid = threadIdx.x;
  int j0 = jg * 16;
  int w = tid >> 6;
  int lane = tid & 63;
  int n16 = lane & 15;
  int qd = lane >> 4;
  int r0 = w * 16;                     // chunk-row tile of this wave
  int dkbase = w * 32;                 // S dk-rows owned by this wave

  __shared__ __align__(16) unsigned short sk[CC * 136];   // 17408 B [c][dk]
  __shared__ __align__(16) unsigned short sq[CC * 136];   // 17408 B
  __shared__ __align__(16) unsigned short sT[CC * 72];    //  9216 B [i][j]
  __shared__ __align__(16) unsigned short sA[CC * 72];    //  9216 B
  __shared__ __align__(16) unsigned short sSb[16 * 136];  //  4352 B S^T: [col][dk]
  __shared__ __align__(16) unsigned short sxT[16 * 72];   //  2304 B x^T: [col][c]
  __shared__ __align__(16) unsigned short svT[16 * 72];   //  2304 B vi^T
  __shared__ float sb[CC];                                //   256 B (total 62464)

  f4 S0 = {0.f, 0.f, 0.f, 0.f}, S1 = {0.f, 0.f, 0.f, 0.f};
  for (int i = tid; i < 16 * 136; i += 256) sSb[i] = 0;

  int bhBase = (b * HH + h) * NN;

  uint4 pk[4], pq[4], pt[2], pa[2];
  float4 pv;
  float pb = 0.f;

  // prefetch chunk 0
  {
#pragma unroll
    for (int p = 0; p < 4; p++) {
      int id = p * 256 + tid, row = id >> 4, c8 = (id & 15) << 3;
      size_t g = ((size_t)((b * TT + row) * HH + h)) * DKk + c8;
      pk[p] = *(const uint4*)(kn + g);
      pq[p] = *(const uint4*)(qn + g);
    }
    size_t cb = (size_t)bhBase * (CC * CC);
#pragma unroll
    for (int p = 0; p < 2; p++) {
      int id = p * 256 + tid, row = id >> 3, c8 = (id & 7) << 3;
      pt[p] = *(const uint4*)(Tg + cb + row * CC + c8);
      pa[p] = *(const uint4*)(Ag + cb + row * CC + c8);
    }
    {
      int c = tid >> 2, c4 = (tid & 3) << 2;
      pv = *(const float4*)(v + ((size_t)((b * TT + c) * HH + h)) * DVv + j0 + c4);
    }
    if (tid < CC) pb = beta[(size_t)((b * TT + tid) * HH + h)];
  }

  for (int n = 0; n < NN; n++) {
    int t0 = n * CC;
    // ---- stage regs -> LDS
#pragma unroll
    for (int p = 0; p < 4; p++) {
      int id = p * 256 + tid, row = id >> 4, c8 = (id & 15) << 3;
      *(uint4*)&sk[row * 136 + c8] = pk[p];
      *(uint4*)&sq[row * 136 + c8] = pq[p];
    }
#pragma unroll
    for (int p = 0; p < 2; p++) {
      int id = p * 256 + tid, row = id >> 3, c8 = (id & 7) << 3;
      *(uint4*)&sT[row * 72 + c8] = pt[p];
      *(uint4*)&sA[row * 72 + c8] = pa[p];
    }
    {
      int c = tid >> 2, c4 = (tid & 3) << 2;
      sxT[(c4 + 0) * 72 + c] = f2bf(pv.x);
      sxT[(c4 + 1) * 72 + c] = f2bf(pv.y);
      sxT[(c4 + 2) * 72 + c] = f2bf(pv.z);
      sxT[(c4 + 3) * 72 + c] = f2bf(pv.w);
    }
    if (tid < CC) sb[tid] = pb;
    __syncthreads();   // B1: staging visible

    // ---- prefetch next chunk into regs (latency hidden behind compute)
    if (n + 1 < NN) {
      int t0n = t0 + CC;
#pragma unroll
      for (int p = 0; p < 4; p++) {
        int id = p * 256 + tid, row = id >> 4, c8 = (id & 15) << 3;
        size_t g = ((size_t)((b * TT + t0n + row) * HH + h)) * DKk + c8;
        pk[p] = *(const uint4*)(kn + g);
        pq[p] = *(const uint4*)(qn + g);
      }
      size_t cb = (size_t)(bhBase + n + 1) * (CC * CC);
#pragma unroll
      for (int p = 0; p < 2; p++) {
        int id = p * 256 + tid, row = id >> 3, c8 = (id & 7) << 3;
        pt[p] = *(const uint4*)(Tg + cb + row * CC + c8);
        pa[p] = *(const uint4*)(Ag + cb + row * CC + c8);
      }
      {
        int c = tid >> 2, c4 = (tid & 3) << 2;
        pv = *(const float4*)(v + ((size_t)((b * TT + t0n + c) * HH + h)) * DVv + j0 + c4);
      }
      if (tid < CC) pb = beta[(size_t)((b * TT + t0n + tid) * HH + h)];
    }

    // ---- x^T = beta * (v - k@S)^T   (in-place in sxT)
    {
      f4 acc = {0.f, 0.f, 0.f, 0.f};
#pragma unroll
      for (int s = 0; s < 4; s++) {
        bf8 a = *(const bf8*)&sk[(r0 + n16) * 136 + s * 32 + qd * 8];
        bf8 bb = *(const bf8*)&sSb[n16 * 136 + s * 32 + qd * 8];
        acc = __builtin_amdgcn_mfma_f32_16x16x32_bf16(a, bb, acc, 0, 0, 0);
      }
#pragma unroll
      for (int r = 0; r < 4; r++) {
        int c = r0 + qd * 4 + r;
        float vval = bf2f(sxT[n16 * 72 + c]);
        sxT[n16 * 72 + c] = f2bf(sb[c] * (vval - acc[r]));
      }
    }
    __syncthreads();   // B2

    // ---- vi = T @ x -> svT (bf16, transposed)
    {
      f4 acc = {0.f, 0.f, 0.f, 0.f};
#pragma unroll
      for (int s = 0; s < 2; s++) {
        bf8 a = *(const bf8*)&sT[(r0 + n16) * 72 + s * 32 + qd * 8];
        bf8 bb = *(const bf8*)&sxT[n16 * 72 + s * 32 + qd * 8];
        acc = __builtin_amdgcn_mfma_f32_16x16x32_bf16(a, bb, acc, 0, 0, 0);
      }
#pragma unroll
      for (int r = 0; r < 4; r++) {
        int c = r0 + qd * 4 + r;
        svT[n16 * 72 + c] = f2bf(acc[r]);
      }
    }
    __syncthreads();   // B3

    // ---- o = q@S_old + attn@vi -> global
    {
      f4 acc = {0.f, 0.f, 0.f, 0.f};
#pragma unroll
      for (int s = 0; s < 4; s++) {
        bf8 a = *(const bf8*)&sq[(r0 + n16) * 136 + s * 32 + qd * 8];
        bf8 bb = *(const bf8*)&sSb[n16 * 136 + s * 32 + qd * 8];
        acc = __builtin_amdgcn_mfma_f32_16x16x32_bf16(a, bb, acc, 0, 0, 0);
      }
#pragma unroll
      for (int s = 0; s < 2; s++) {
        bf8 a = *(const bf8*)&sA[(r0 + n16) * 72 + s * 32 + qd * 8];
        bf8 bb = *(const bf8*)&svT[n16 * 72 + s * 32 + qd * 8];
        acc = __builtin_amdgcn_mfma_f32_16x16x32_bf16(a, bb, acc, 0, 0, 0);
      }
#pragma unroll
      for (int r = 0; r < 4; r++) {
        int c = r0 + qd * 4 + r;
        o[((size_t)((b * TT + t0 + c) * HH + h)) * DVv + j0 + n16] = acc[r];
      }
    }

    // ---- S += k^T @ vi   (register accumulators, per-wave dk rows)
    {
#pragma unroll
      for (int t = 0; t < 2; t++) {
        int dkt = dkbase + t * 16;
        f4 acc = t ? S1 : S0;
#pragma unroll
        for (int s = 0; s < 2; s++) {
          bf8 a;
#pragma unroll
          for (int j = 0; j < 8; j++)
            a[j] = (short)sk[(s * 32 + qd * 8 + j) * 136 + dkt + n16];
          bf8 bb = *(const bf8*)&svT[n16 * 72 + s * 32 + qd * 8];
          acc = __builtin_amdgcn_mfma_f32_16x16x32_bf16(a, bb, acc, 0, 0, 0);
        }
        if (t) S1 = acc; else S0 = acc;
      }
    }
    __syncthreads();   // B4: all reads of sSb/sk/sq/sxT/svT done

    // ---- write new S (bf16) to sSb
#pragma unroll
    for (int r = 0; r < 4; r++) {
      sSb[n16 * 136 + dkbase + qd * 4 + r] = f2bf(S0[r]);
      sSb[n16 * 136 + dkbase + 16 + qd * 4 + r] = f2bf(S1[r]);
    }
  }
}

// ---------------------------------------------------------------------------
// K5: in-place on d_out: RMSNorm(o)*o_norm_w * swish(g), then per-head
//     projection out[t, h*128+d] = sum_v o~[v] * P[h,v,d].
// ---------------------------------------------------------------------------
__global__ __launch_bounds__(256) void k5_out(
    const float* __restrict__ graw, const float* __restrict__ onw,
    const float* __restrict__ opw, float* __restrict__ out) {
  int bi = blockIdx.x;                  // B*(T/32)*H = 4096
  int h = bi & (HH - 1);
  int tt = (bi >> 4) & 127;
  int b = bi >> 11;
  int t0 = tt * 32;
  int tid = threadIdx.x;

  __shared__ __align__(16) unsigned short sP[DVv * DKk];  // 32768 B (bf16)
  __shared__ __align__(16) float so[32 * 129];            // 16512 B
  __shared__ float smul[32];
  __shared__ float snw[DVv];

  const float* P = opw + (size_t)h * DVv * DKk;
  for (int r = 0; r < 16; r++) {
    int idx4 = r * 256 + tid;           // 4096 quads
    float4 pvv = *(const float4*)(P + ((size_t)idx4 << 2));
    unsigned p0 = (unsigned)f2bf(pvv.x) | ((unsigned)f2bf(pvv.y) << 16);
    unsigned p1 = (unsigned)f2bf(pvv.z) | ((unsigned)f2bf(pvv.w) << 16);
    *(uint2*)&sP[idx4 << 2] = make_uint2(p0, p1);
  }
  for (int r = 0; r < 16; r++) {
    int idx = r * 256 + tid;
    int t = idx >> 7, d = idx & 127;
    so[t * 129 + d] = out[((size_t)((b * TT + t0 + t) * HH + h)) * DVv + d];
  }
  if (tid < DVv) snw[tid] = onw[tid];
  __syncthreads();

  {
    int t = tid >> 3, l8 = tid & 7;
    float ss = 0.f;
    for (int j = 0; j < 16; j++) { float x = so[t * 129 + l8 + (j << 3)]; ss += x * x; }
    ss += __shfl_down(ss, 4, 8);
    ss += __shfl_down(ss, 2, 8);
    ss += __shfl_down(ss, 1, 8);
    if (l8 == 0) {
      float rms = rsqrtf(ss * (1.f / 128.f) + 1e-5f);
      float gv = graw[(size_t)((b * TT + t0 + t) * HH + h)];
      float sig = 1.f / (1.f + expf(-gv));
      smul[t] = rms * gv * sig;
    }
  }
  __syncthreads();
  for (int r = 0; r < 16; r++) {
    int idx = r * 256 + tid;
    int t = idx >> 7, d = idx & 127;
    so[t * 129 + d] *= smul[t] * snw[d];
  }
  __syncthreads();

  {
    int ttile = tid >> 5;               // 4 tokens each
    int dt = tid & 31;                  // 4 output dims each
    int tb = ttile << 2;
    int d0 = dt << 2;
    float acc[4][4];
#pragma unroll
    for (int a = 0; a < 4; a++)
#pragma unroll
      for (int e = 0; e < 4; e++) acc[a][e] = 0.f;
    for (int vv = 0; vv < DVv; vv++) {
      uint2 u = *(const uint2*)&sP[vv * DKk + d0];
      float p0 = __uint_as_float(u.x << 16);
      float p1 = __uint_as_float(u.x & 0xffff0000u);
      float p2 = __uint_as_float(u.y << 16);
      float p3 = __uint_as_float(u.y & 0xffff0000u);
#pragma unroll
      for (int a = 0; a < 4; a++) {
        float ov = so[(tb + a) * 129 + vv];
        acc[a][0] += ov * p0; acc[a][1] += ov * p1; acc[a][2] += ov * p2; acc[a][3] += ov * p3;
      }
    }
#pragma unroll
    for (int a = 0; a < 4; a++) {
      size_t go = ((size_t)((b * TT + t0 + tb + a) * HH + h)) * DKk + d0;
      float4 r; r.x = acc[a][0]; r.y = acc[a][1]; r.z = acc[a][2]; r.w = acc[a][3];
      *(float4*)(out + go) = r;
    }
  }
}

// ---------------------------------------------------------------------------
extern "C" void kernel_launch(void* const* d_in, const int* in_sizes, int n_in,
                              void* d_out, int out_size, void* d_ws, size_t ws_size,
                              hipStream_t stream) {
  (void)in_sizes; (void)n_in; (void)out_size; (void)ws_size;
  const float* hab = (const float*)d_in[0];
  const float* hg  = (const float*)d_in[1];
  const float* q   = (const float*)d_in[2];
  const float* k   = (const float*)d_in[3];
  const float* v   = (const float*)d_in[4];
  const float* Wb  = (const float*)d_in[5];
  const float* Wg  = (const float*)d_in[6];
  const float* onw = (const float*)d_in[7];
  const float* opw = (const float*)d_in[8];
  float* out = (float*)d_out;

  // ws layout (bytes): beta 512K | graw 512K | qn 32M | kn 32M | T 16M | attn 16M
  char* ws = (char*)d_ws;
  float* beta          = (float*)(ws);
  float* graw          = (float*)(ws + 524288);
  unsigned short* qn   = (unsigned short*)(ws + 1048576);
  unsigned short* kn   = (unsigned short*)(ws + 34603008);
  unsigned short* Tg   = (unsigned short*)(ws + 68157440);
  unsigned short* Ag   = (unsigned short*)(ws + 84934656);

  hipLaunchKernelGGL(k1_beta_g, dim3(BB * TT), dim3(256), 0, stream,
                     hab, hg, Wb, Wg, beta, graw);
  hipLaunchKernelGGL(k2_l2norm, dim3(BB * TT * HH / 8), dim3(256), 0, stream,
                     q, k, qn, kn);
  hipLaunchKernelGGL(k3_chunk, dim3(BB * HH * NN), dim3(256), 0, stream,
                     qn, kn, beta, Tg, Ag);
  hipLaunchKernelGGL(k4_scan, dim3(BB * HH * GG), dim3(256), 0, stream,
                     qn, kn, v, beta, Tg, Ag, out);
  hipLaunchKernelGGL(k5_out, dim3(BB * (TT / 32) * HH), dim3(256), 0, stream,
                     graw, onw, opw, out);
}

// Round 4
// 647.523 us; speedup vs baseline: 2.9505x; 1.3441x over previous
//
#include <hip/hip_runtime.h>
#include <hip/hip_bf16.h>

// Problem constants (DeltaNet_6614249636545)
#define BB 2
#define TT 4096
#define HH 16
#define DKk 128
#define DVv 128
#define HIDD 2048
#define CC 64
#define NN 64          // TT / CC
#define GG 8           // dv column groups in scan kernel
#define QSCALE 0.08838834764831845f  // 128^-0.5

static __device__ __forceinline__ unsigned short f2bf(float f) {
  unsigned u = __float_as_uint(f);
  u += 0x7fffu + ((u >> 16) & 1u);   // round-to-nearest-even
  return (unsigned short)(u >> 16);
}
static __device__ __forceinline__ float bf2f(unsigned short s) {
  return __uint_as_float(((unsigned)s) << 16);
}

typedef short bf8 __attribute__((ext_vector_type(8)));
typedef float f4 __attribute__((ext_vector_type(4)));

// ---------------------------------------------------------------------------
// K0: transpose + bf16-cast projection weights: W[k][h] fp32 -> Wt[h][k] bf16
// blocks 0-7: Wb chunk k0=blk*256; blocks 8-15: Wg. Tiny prep kernel.
// ---------------------------------------------------------------------------
__global__ __launch_bounds__(256) void k0_wt(
    const float* __restrict__ Wb, const float* __restrict__ Wg,
    unsigned short* __restrict__ Wtb, unsigned short* __restrict__ Wtg) {
  int blk = blockIdx.x;
  const float* W = (blk < 8) ? Wb : Wg;
  unsigned short* Wt = (blk < 8) ? Wtb : Wtg;
  int k0 = (blk & 7) * 256;
  int tid = threadIdx.x;
  __shared__ unsigned short st[16][272];
  const float* p = W + (size_t)(k0 + tid) * HH;
#pragma unroll
  for (int h4 = 0; h4 < 4; h4++) {
    float4 x = *(const float4*)(p + h4 * 4);
    st[h4 * 4 + 0][tid] = f2bf(x.x);
    st[h4 * 4 + 1][tid] = f2bf(x.y);
    st[h4 * 4 + 2][tid] = f2bf(x.z);
    st[h4 * 4 + 3][tid] = f2bf(x.w);
  }
  __syncthreads();
  int h = tid >> 4, c = (tid & 15) << 4;
#pragma unroll
  for (int j = 0; j < 16; j++)
    Wt[(size_t)h * HIDD + k0 + c + j] = st[h][c + j];
}

// ---------------------------------------------------------------------------
// K1 (MFMA): beta = sigmoid(hab @ Wb), graw = hg @ Wg as skinny GEMM.
// Wave job = (16-token tile = blockIdx, proj = w>>1, khalf = w&1); K=1024 per
// wave (32 MFMA steps); K-split pair reduces via LDS; proj-0 applies sigmoid.
// ---------------------------------------------------------------------------
__global__ __launch_bounds__(256) void k1_beta_g(
    const float* __restrict__ hab, const float* __restrict__ hg,
    const unsigned short* __restrict__ Wtb, const unsigned short* __restrict__ Wtg,
    float* __restrict__ beta, float* __restrict__ graw) {
  int tile = blockIdx.x;               // 512 tiles of 16 tokens
  int tid = threadIdx.x;
  int w = tid >> 6, lane = tid & 63;
  int proj = w >> 1, ks = w & 1;
  int n16 = lane & 15, qd = lane >> 4;
  const float* hid = proj ? hg : hab;
  const unsigned short* Wt = proj ? Wtg : Wtb;
  size_t rowbase = (size_t)(tile * 16 + n16) * HIDD;
  int k0 = ks * 1024;

  f4 acc = {0.f, 0.f, 0.f, 0.f};
  for (int s = 0; s < 32; s++) {
    int kk = k0 + s * 32 + qd * 8;
    const float* hp = hid + rowbase + kk;
    float4 h0 = *(const float4*)hp;
    float4 h1 = *(const float4*)(hp + 4);
    bf8 a;
    a[0] = (short)f2bf(h0.x); a[1] = (short)f2bf(h0.y);
    a[2] = (short)f2bf(h0.z); a[3] = (short)f2bf(h0.w);
    a[4] = (short)f2bf(h1.x); a[5] = (short)f2bf(h1.y);
    a[6] = (short)f2bf(h1.z); a[7] = (short)f2bf(h1.w);
    bf8 b = *(const bf8*)&Wt[(size_t)n16 * HIDD + kk];
    acc = __builtin_amdgcn_mfma_f32_16x16x32_bf16(a, b, acc, 0, 0, 0);
  }

  __shared__ float red[2][16][17];
  if (ks == 1) {
#pragma unroll
    for (int r = 0; r < 4; r++) red[proj][qd * 4 + r][n16] = acc[r];
  }
  __syncthreads();
  if (ks == 0) {
#pragma unroll
    for (int r = 0; r < 4; r++) {
      float s = acc[r] + red[proj][qd * 4 + r][n16];
      size_t t = (size_t)(tile * 16 + qd * 4 + r) * HH + n16;
      if (proj == 0) beta[t] = 1.f / (1.f + expf(-s));
      else           graw[t] = s;
    }
  }
}

// ---------------------------------------------------------------------------
// K2: l2norm(q)*scale -> qn (bf16), l2norm(k) -> kn (bf16)
// ---------------------------------------------------------------------------
__global__ __launch_bounds__(256) void k2_l2norm(
    const float* __restrict__ q, const float* __restrict__ k,
    unsigned short* __restrict__ qn, unsigned short* __restrict__ kn) {
  int lane = threadIdx.x & 63, wave = threadIdx.x >> 6;
  for (int u = 0; u < 2; u++) {
    int vec = blockIdx.x * 8 + wave * 2 + u;
    size_t off = (size_t)vec * 64 + lane;
    float2 q2 = ((const float2*)q)[off];
    float2 k2 = ((const float2*)k)[off];
    float sq = q2.x * q2.x + q2.y * q2.y;
    float sk = k2.x * k2.x + k2.y * k2.y;
#pragma unroll
    for (int m = 32; m; m >>= 1) { sq += __shfl_xor(sq, m); sk += __shfl_xor(sk, m); }
    float rq = rsqrtf(sq + 1e-6f) * QSCALE;
    float rk = rsqrtf(sk + 1e-6f);
    unsigned pq = (unsigned)f2bf(q2.x * rq) | ((unsigned)f2bf(q2.y * rq) << 16);
    unsigned pk = (unsigned)f2bf(k2.x * rk) | ((unsigned)f2bf(k2.y * rk) << 16);
    ((unsigned*)qn)[off] = pq;
    ((unsigned*)kn)[off] = pk;
  }
}

// ---------------------------------------------------------------------------
// K3 (MFMA): per chunk: attn = tril(q k^T) -> Ag,
//   A = tril(k_beta k^T,-1), T = (I+A)^{-1} -> Tg via nilpotent doubling.
// ---------------------------------------------------------------------------
#define SW 72          // stride (shorts) of 64x64 bf16 mats
#define O_M0R 0        // offsets in shorts
#define O_M0T 4608
#define O_M1R 9216
#define O_M1T 13824
#define O_TB  18432    // T^T (col-major shadow of T), bf16
#define ARENA_SH 23040

__global__ __launch_bounds__(256) void k3_chunk(
    const unsigned short* __restrict__ qn, const unsigned short* __restrict__ kn,
    const float* __restrict__ beta,
    unsigned short* __restrict__ Tg, unsigned short* __restrict__ Ag) {
  int cid = blockIdx.x;
  int n = cid & (NN - 1);
  int bh = cid / NN;
  int h = bh & (HH - 1);
  int b = bh / HH;
  int tid = threadIdx.x;
  int w = tid >> 6;
  int lane = tid & 63;
  int n16 = lane & 15;
  int qd = lane >> 4;
  int r0 = w * 16;

  __shared__ __align__(16) unsigned short arena[ARENA_SH];  // 46080 B
  __shared__ float sb[CC];
  unsigned short* sk = arena;           // [c][dk] stride 136, 8704 shorts
  unsigned short* sq = arena + 8704;    // aliased by M buffers after init

  int t0 = n * CC;
#pragma unroll
  for (int p = 0; p < 4; p++) {
    int id = p * 256 + tid, row = id >> 4, c8 = (id & 15) << 3;
    size_t g = ((size_t)((b * TT + t0 + row) * HH + h)) * DKk + c8;
    *(uint4*)&sk[row * 136 + c8] = *(const uint4*)(kn + g);
    *(uint4*)&sq[row * 136 + c8] = *(const uint4*)(qn + g);
  }
  if (tid < CC) sb[tid] = beta[(size_t)((b * TT + t0 + tid) * HH + h)];
  __syncthreads();

  // ---- attn = q k^T and raw kk = k k^T   (MFMA, K=128)
  f4 at[4], mk[4];
#pragma unroll
  for (int ct = 0; ct < 4; ct++) { at[ct] = (f4){0,0,0,0}; mk[ct] = (f4){0,0,0,0}; }
#pragma unroll
  for (int s = 0; s < 4; s++) {
    bf8 aq = *(const bf8*)&sq[(r0 + n16) * 136 + s * 32 + qd * 8];
    bf8 ak = *(const bf8*)&sk[(r0 + n16) * 136 + s * 32 + qd * 8];
#pragma unroll
    for (int ct = 0; ct < 4; ct++) {
      bf8 bk = *(const bf8*)&sk[(ct * 16 + n16) * 136 + s * 32 + qd * 8];
      at[ct] = __builtin_amdgcn_mfma_f32_16x16x32_bf16(aq, bk, at[ct], 0, 0, 0);
      mk[ct] = __builtin_amdgcn_mfma_f32_16x16x32_bf16(ak, bk, mk[ct], 0, 0, 0);
    }
  }

  size_t abase = (size_t)cid * (CC * CC);
  f4 tf[4];
  float mpv[4][4];
#pragma unroll
  for (int ct = 0; ct < 4; ct++) {
#pragma unroll
    for (int r = 0; r < 4; r++) {
      int i = r0 + qd * 4 + r, j = ct * 16 + n16;
      Ag[abase + i * CC + j] = f2bf((j <= i) ? at[ct][r] : 0.f);
      float mp = (j < i) ? -sb[i] * mk[ct][r] : 0.f;
      mpv[ct][r] = mp;
      tf[ct][r] = (i == j) ? 1.f : mp;
    }
  }
  __syncthreads();   // reads of sk/sq done; arena can be re-purposed

#pragma unroll
  for (int ct = 0; ct < 4; ct++) {
#pragma unroll
    for (int r = 0; r < 4; r++) {
      int i = r0 + qd * 4 + r, j = ct * 16 + n16;
      unsigned short hm = f2bf(mpv[ct][r]);
      arena[O_M0R + i * SW + j] = hm;
      arena[O_M0T + j * SW + i] = hm;
      arena[O_TB + j * SW + i] = f2bf(tf[ct][r]);
    }
  }
  __syncthreads();

  int p = 0;
  for (int it = 1; it <= 5; it++) {
    int mrp = p ? O_M1R : O_M0R, mtp = p ? O_M1T : O_M0T;
    int mrn = p ? O_M0R : O_M1R, mtn = p ? O_M0T : O_M1T;
    f4 nr[4];
#pragma unroll
    for (int ct = 0; ct < 4; ct++) nr[ct] = (f4){0,0,0,0};
#pragma unroll
    for (int s = 0; s < 2; s++) {
      bf8 a = *(const bf8*)&arena[mrp + (r0 + n16) * SW + s * 32 + qd * 8];
#pragma unroll
      for (int ct = 0; ct < 4; ct++) {
        bf8 bb = *(const bf8*)&arena[mtp + (ct * 16 + n16) * SW + s * 32 + qd * 8];
        nr[ct] = __builtin_amdgcn_mfma_f32_16x16x32_bf16(a, bb, nr[ct], 0, 0, 0);
      }
    }
#pragma unroll
    for (int ct = 0; ct < 4; ct++) {
#pragma unroll
      for (int r = 0; r < 4; r++) {
        int i = r0 + qd * 4 + r, j = ct * 16 + n16;
        unsigned short hm = f2bf(nr[ct][r]);
        arena[mrn + i * SW + j] = hm;
        arena[mtn + j * SW + i] = hm;
      }
    }
    __syncthreads();  // B1

    // phase B: Tf += N · T
#pragma unroll
    for (int s = 0; s < 2; s++) {
      bf8 a = *(const bf8*)&arena[mrn + (r0 + n16) * SW + s * 32 + qd * 8];
#pragma unroll
      for (int ct = 0; ct < 4; ct++) {
        bf8 bb = *(const bf8*)&arena[O_TB + (ct * 16 + n16) * SW + s * 32 + qd * 8];
        tf[ct] = __builtin_amdgcn_mfma_f32_16x16x32_bf16(a, bb, tf[ct], 0, 0, 0);
      }
    }
    __syncthreads();  // B2

    if (it < 5) {
#pragma unroll
      for (int ct = 0; ct < 4; ct++) {
#pragma unroll
        for (int r = 0; r < 4; r++) {
          int i = r0 + qd * 4 + r, j = ct * 16 + n16;
          arena[O_TB + j * SW + i] = f2bf(tf[ct][r]);
        }
      }
    }
    p = 1 - p;
  }

#pragma unroll
  for (int ct = 0; ct < 4; ct++) {
#pragma unroll
    for (int r = 0; r < 4; r++) {
      int i = r0 + qd * 4 + r, j = ct * 16 + n16;
      Tg[abase + i * CC + j] = f2bf(tf[ct][r]);
    }
  }
}

// ---------------------------------------------------------------------------
// K4 (MFMA): sequential chunk scan. block = (b,h,jg), 16 DV cols, 4 waves.
// ---------------------------------------------------------------------------
__global__ __launch_bounds__(256) void k4_scan(
    const unsigned short* __restrict__ qn, const unsigned short* __restrict__ kn,
    const float* __restrict__ v, const float* __restrict__ beta,
    const unsigned short* __restrict__ Tg, const unsigned short* __restrict__ Ag,
    float* __restrict__ o) {
  int bi = blockIdx.x;                 // jg*32 + bh
  int jg = bi >> 5;
  int bh = bi & 31;
  int h = bh & (HH - 1);
  int b = bh >> 4;
  int tid = threadIdx.x;
  int j0 = jg * 16;
  int w = tid >> 6;
  int lane = tid & 63;
  int n16 = lane & 15;
  int qd = lane >> 4;
  int r0 = w * 16;                     // chunk-row tile of this wave
  int dkbase = w * 32;                 // S dk-rows owned by this wave

  __shared__ __align__(16) unsigned short sk[CC * 136];   // 17408 B [c][dk]
  __shared__ __align__(16) unsigned short sq[CC * 136];   // 17408 B
  __shared__ __align__(16) unsigned short sT[CC * 72];    //  9216 B [i][j]
  __shared__ __align__(16) unsigned short sA[CC * 72];    //  9216 B
  __shared__ __align__(16) unsigned short sSb[16 * 136];  //  4352 B S^T: [col][dk]
  __shared__ __align__(16) unsigned short sxT[16 * 72];   //  2304 B x^T: [col][c]
  __shared__ __align__(16) unsigned short svT[16 * 72];   //  2304 B vi^T
  __shared__ float sb[CC];                                //   256 B (total 62464)

  f4 S0 = {0.f, 0.f, 0.f, 0.f}, S1 = {0.f, 0.f, 0.f, 0.f};
  for (int i = tid; i < 16 * 136; i += 256) sSb[i] = 0;

  int bhBase = (b * HH + h) * NN;

  uint4 pk[4], pq[4], pt[2], pa[2];
  float4 pv;
  float pb = 0.f;

  // prefetch chunk 0
  {
#pragma unroll
    for (int p = 0; p < 4; p++) {
      int id = p * 256 + tid, row = id >> 4, c8 = (id & 15) << 3;
      size_t g = ((size_t)((b * TT + row) * HH + h)) * DKk + c8;
      pk[p] = *(const uint4*)(kn + g);
      pq[p] = *(const uint4*)(qn + g);
    }
    size_t cb = (size_t)bhBase * (CC * CC);
#pragma unroll
    for (int p = 0; p < 2; p++) {
      int id = p * 256 + tid, row = id >> 3, c8 = (id & 7) << 3;
      pt[p] = *(const uint4*)(Tg + cb + row * CC + c8);
      pa[p] = *(const uint4*)(Ag + cb + row * CC + c8);
    }
    {
      int c = tid >> 2, c4 = (tid & 3) << 2;
      pv = *(const float4*)(v + ((size_t)((b * TT + c) * HH + h)) * DVv + j0 + c4);
    }
    if (tid < CC) pb = beta[(size_t)((b * TT + tid) * HH + h)];
  }

  for (int n = 0; n < NN; n++) {
    int t0 = n * CC;
    // ---- stage regs -> LDS
#pragma unroll
    for (int p = 0; p < 4; p++) {
      int id = p * 256 + tid, row = id >> 4, c8 = (id & 15) << 3;
      *(uint4*)&sk[row * 136 + c8] = pk[p];
      *(uint4*)&sq[row * 136 + c8] = pq[p];
    }
#pragma unroll
    for (int p = 0; p < 2; p++) {
      int id = p * 256 + tid, row = id >> 3, c8 = (id & 7) << 3;
      *(uint4*)&sT[row * 72 + c8] = pt[p];
      *(uint4*)&sA[row * 72 + c8] = pa[p];
    }
    {
      int c = tid >> 2, c4 = (tid & 3) << 2;
      sxT[(c4 + 0) * 72 + c] = f2bf(pv.x);
      sxT[(c4 + 1) * 72 + c] = f2bf(pv.y);
      sxT[(c4 + 2) * 72 + c] = f2bf(pv.z);
      sxT[(c4 + 3) * 72 + c] = f2bf(pv.w);
    }
    if (tid < CC) sb[tid] = pb;
    __syncthreads();   // B1: staging visible

    // ---- prefetch next chunk into regs
    if (n + 1 < NN) {
      int t0n = t0 + CC;
#pragma unroll
      for (int p = 0; p < 4; p++) {
        int id = p * 256 + tid, row = id >> 4, c8 = (id & 15) << 3;
        size_t g = ((size_t)((b * TT + t0n + row) * HH + h)) * DKk + c8;
        pk[p] = *(const uint4*)(kn + g);
        pq[p] = *(const uint4*)(qn + g);
      }
      size_t cb = (size_t)(bhBase + n + 1) * (CC * CC);
#pragma unroll
      for (int p = 0; p < 2; p++) {
        int id = p * 256 + tid, row = id >> 3, c8 = (id & 7) << 3;
        pt[p] = *(const uint4*)(Tg + cb + row * CC + c8);
        pa[p] = *(const uint4*)(Ag + cb + row * CC + c8);
      }
      {
        int c = tid >> 2, c4 = (tid & 3) << 2;
        pv = *(const float4*)(v + ((size_t)((b * TT + t0n + c) * HH + h)) * DVv + j0 + c4);
      }
      if (tid < CC) pb = beta[(size_t)((b * TT + t0n + tid) * HH + h)];
    }

    // ---- x^T = beta * (v - k@S)^T   (in-place in sxT)
    {
      f4 acc = {0.f, 0.f, 0.f, 0.f};
#pragma unroll
      for (int s = 0; s < 4; s++) {
        bf8 a = *(const bf8*)&sk[(r0 + n16) * 136 + s * 32 + qd * 8];
        bf8 bb = *(const bf8*)&sSb[n16 * 136 + s * 32 + qd * 8];
        acc = __builtin_amdgcn_mfma_f32_16x16x32_bf16(a, bb, acc, 0, 0, 0);
      }
#pragma unroll
      for (int r = 0; r < 4; r++) {
        int c = r0 + qd * 4 + r;
        float vval = bf2f(sxT[n16 * 72 + c]);
        sxT[n16 * 72 + c] = f2bf(sb[c] * (vval - acc[r]));
      }
    }
    __syncthreads();   // B2

    // ---- vi = T @ x -> svT (bf16, transposed)
    {
      f4 acc = {0.f, 0.f, 0.f, 0.f};
#pragma unroll
      for (int s = 0; s < 2; s++) {
        bf8 a = *(const bf8*)&sT[(r0 + n16) * 72 + s * 32 + qd * 8];
        bf8 bb = *(const bf8*)&sxT[n16 * 72 + s * 32 + qd * 8];
        acc = __builtin_amdgcn_mfma_f32_16x16x32_bf16(a, bb, acc, 0, 0, 0);
      }
#pragma unroll
      for (int r = 0; r < 4; r++) {
        int c = r0 + qd * 4 + r;
        svT[n16 * 72 + c] = f2bf(acc[r]);
      }
    }
    __syncthreads();   // B3

    // ---- o = q@S_old + attn@vi -> global
    {
      f4 acc = {0.f, 0.f, 0.f, 0.f};
#pragma unroll
      for (int s = 0; s < 4; s++) {
        bf8 a = *(const bf8*)&sq[(r0 + n16) * 136 + s * 32 + qd * 8];
        bf8 bb = *(const bf8*)&sSb[n16 * 136 + s * 32 + qd * 8];
        acc = __builtin_amdgcn_mfma_f32_16x16x32_bf16(a, bb, acc, 0, 0, 0);
      }
#pragma unroll
      for (int s = 0; s < 2; s++) {
        bf8 a = *(const bf8*)&sA[(r0 + n16) * 72 + s * 32 + qd * 8];
        bf8 bb = *(const bf8*)&svT[n16 * 72 + s * 32 + qd * 8];
        acc = __builtin_amdgcn_mfma_f32_16x16x32_bf16(a, bb, acc, 0, 0, 0);
      }
#pragma unroll
      for (int r = 0; r < 4; r++) {
        int c = r0 + qd * 4 + r;
        o[((size_t)((b * TT + t0 + c) * HH + h)) * DVv + j0 + n16] = acc[r];
      }
    }

    // ---- S += k^T @ vi   (register accumulators, per-wave dk rows)
    {
#pragma unroll
      for (int t = 0; t < 2; t++) {
        int dkt = dkbase + t * 16;
        f4 acc = t ? S1 : S0;
#pragma unroll
        for (int s = 0; s < 2; s++) {
          bf8 a;
#pragma unroll
          for (int j = 0; j < 8; j++)
            a[j] = (short)sk[(s * 32 + qd * 8 + j) * 136 + dkt + n16];
          bf8 bb = *(const bf8*)&svT[n16 * 72 + s * 32 + qd * 8];
          acc = __builtin_amdgcn_mfma_f32_16x16x32_bf16(a, bb, acc, 0, 0, 0);
        }
        if (t) S1 = acc; else S0 = acc;
      }
    }
    __syncthreads();   // B4

    // ---- write new S (bf16) to sSb
#pragma unroll
    for (int r = 0; r < 4; r++) {
      sSb[n16 * 136 + dkbase + qd * 4 + r] = f2bf(S0[r]);
      sSb[n16 * 136 + dkbase + 16 + qd * 4 + r] = f2bf(S1[r]);
    }
  }
}

// ---------------------------------------------------------------------------
// K5: in-place on d_out: RMSNorm(o)*o_norm_w * swish(g), then per-head
//     projection out[t, h*128+d] = sum_v o~[v] * P[h,v,d].
// ---------------------------------------------------------------------------
__global__ __launch_bounds__(256) void k5_out(
    const float* __restrict__ graw, const float* __restrict__ onw,
    const float* __restrict__ opw, float* __restrict__ out) {
  int bi = blockIdx.x;                  // B*(T/32)*H = 4096
  int h = bi & (HH - 1);
  int tt = (bi >> 4) & 127;
  int b = bi >> 11;
  int t0 = tt * 32;
  int tid = threadIdx.x;

  __shared__ __align__(16) unsigned short sP[DVv * DKk];  // 32768 B (bf16)
  __shared__ __align__(16) float so[32 * 129];            // 16512 B
  __shared__ float smul[32];
  __shared__ float snw[DVv];

  const float* P = opw + (size_t)h * DVv * DKk;
  for (int r = 0; r < 16; r++) {
    int idx4 = r * 256 + tid;           // 4096 quads
    float4 pvv = *(const float4*)(P + ((size_t)idx4 << 2));
    unsigned p0 = (unsigned)f2bf(pvv.x) | ((unsigned)f2bf(pvv.y) << 16);
    unsigned p1 = (unsigned)f2bf(pvv.z) | ((unsigned)f2bf(pvv.w) << 16);
    *(uint2*)&sP[idx4 << 2] = make_uint2(p0, p1);
  }
  for (int r = 0; r < 16; r++) {
    int idx = r * 256 + tid;
    int t = idx >> 7, d = idx & 127;
    so[t * 129 + d] = out[((size_t)((b * TT + t0 + t) * HH + h)) * DVv + d];
  }
  if (tid < DVv) snw[tid] = onw[tid];
  __syncthreads();

  {
    int t = tid >> 3, l8 = tid & 7;
    float ss = 0.f;
    for (int j = 0; j < 16; j++) { float x = so[t * 129 + l8 + (j << 3)]; ss += x * x; }
    ss += __shfl_down(ss, 4, 8);
    ss += __shfl_down(ss, 2, 8);
    ss += __shfl_down(ss, 1, 8);
    if (l8 == 0) {
      float rms = rsqrtf(ss * (1.f / 128.f) + 1e-5f);
      float gv = graw[(size_t)((b * TT + t0 + t) * HH + h)];
      float sig = 1.f / (1.f + expf(-gv));
      smul[t] = rms * gv * sig;
    }
  }
  __syncthreads();
  for (int r = 0; r < 16; r++) {
    int idx = r * 256 + tid;
    int t = idx >> 7, d = idx & 127;
    so[t * 129 + d] *= smul[t] * snw[d];
  }
  __syncthreads();

  {
    int ttile = tid >> 5;               // 4 tokens each
    int dt = tid & 31;                  // 4 output dims each
    int tb = ttile << 2;
    int d0 = dt << 2;
    float acc[4][4];
#pragma unroll
    for (int a = 0; a < 4; a++)
#pragma unroll
      for (int e = 0; e < 4; e++) acc[a][e] = 0.f;
    for (int vv = 0; vv < DVv; vv++) {
      uint2 u = *(const uint2*)&sP[vv * DKk + d0];
      float p0 = __uint_as_float(u.x << 16);
      float p1 = __uint_as_float(u.x & 0xffff0000u);
      float p2 = __uint_as_float(u.y << 16);
      float p3 = __uint_as_float(u.y & 0xffff0000u);
#pragma unroll
      for (int a = 0; a < 4; a++) {
        float ov = so[(tb + a) * 129 + vv];
        acc[a][0] += ov * p0; acc[a][1] += ov * p1; acc[a][2] += ov * p2; acc[a][3] += ov * p3;
      }
    }
#pragma unroll
    for (int a = 0; a < 4; a++) {
      size_t go = ((size_t)((b * TT + t0 + tb + a) * HH + h)) * DKk + d0;
      float4 r; r.x = acc[a][0]; r.y = acc[a][1]; r.z = acc[a][2]; r.w = acc[a][3];
      *(float4*)(out + go) = r;
    }
  }
}

// ---------------------------------------------------------------------------
extern "C" void kernel_launch(void* const* d_in, const int* in_sizes, int n_in,
                              void* d_out, int out_size, void* d_ws, size_t ws_size,
                              hipStream_t stream) {
  (void)in_sizes; (void)n_in; (void)out_size; (void)ws_size;
  const float* hab = (const float*)d_in[0];
  const float* hg  = (const float*)d_in[1];
  const float* q   = (const float*)d_in[2];
  const float* k   = (const float*)d_in[3];
  const float* v   = (const float*)d_in[4];
  const float* Wb  = (const float*)d_in[5];
  const float* Wg  = (const float*)d_in[6];
  const float* onw = (const float*)d_in[7];
  const float* opw = (const float*)d_in[8];
  float* out = (float*)d_out;

  // ws layout (bytes): beta 512K | graw 512K | qn 32M | kn 32M | T 16M | attn 16M
  //                    | Wtb 64K | Wtg 64K
  char* ws = (char*)d_ws;
  float* beta          = (float*)(ws);
  float* graw          = (float*)(ws + 524288);
  unsigned short* qn   = (unsigned short*)(ws + 1048576);
  unsigned short* kn   = (unsigned short*)(ws + 34603008);
  unsigned short* Tg   = (unsigned short*)(ws + 68157440);
  unsigned short* Ag   = (unsigned short*)(ws + 84934656);
  unsigned short* Wtb  = (unsigned short*)(ws + 101711872);
  unsigned short* Wtg  = (unsigned short*)(ws + 101777408);

  hipLaunchKernelGGL(k0_wt, dim3(16), dim3(256), 0, stream,
                     Wb, Wg, Wtb, Wtg);
  hipLaunchKernelGGL(k1_beta_g, dim3(TT * BB / 16), dim3(256), 0, stream,
                     hab, hg, Wtb, Wtg, beta, graw);
  hipLaunchKernelGGL(k2_l2norm, dim3(BB * TT * HH / 8), dim3(256), 0, stream,
                     q, k, qn, kn);
  hipLaunchKernelGGL(k3_chunk, dim3(BB * HH * NN), dim3(256), 0, stream,
                     qn, kn, beta, Tg, Ag);
  hipLaunchKernelGGL(k4_scan, dim3(BB * HH * GG), dim3(256), 0, stream,
                     qn, kn, v, beta, Tg, Ag, out);
  hipLaunchKernelGGL(k5_out, dim3(BB * (TT / 32) * HH), dim3(256), 0, stream,
                     graw, onw, opw, out);
}

// Round 5
// 644.923 us; speedup vs baseline: 2.9624x; 1.0040x over previous
//
#include <hip/hip_runtime.h>
#include <hip/hip_bf16.h>

// Problem constants (DeltaNet_6614249636545)
#define BB 2
#define TT 4096
#define HH 16
#define DKk 128
#define DVv 128
#define HIDD 2048
#define CC 64
#define NN 64          // TT / CC
#define GG 8           // dv column groups in scan kernel
#define QSCALE 0.08838834764831845f  // 128^-0.5

static __device__ __forceinline__ unsigned short f2bf(float f) {
  unsigned u = __float_as_uint(f);
  u += 0x7fffu + ((u >> 16) & 1u);   // round-to-nearest-even
  return (unsigned short)(u >> 16);
}
static __device__ __forceinline__ float bf2f(unsigned short s) {
  return __uint_as_float(((unsigned)s) << 16);
}

// Barrier that drains ONLY LDS (lgkmcnt), leaving global loads in flight.
// Safe when the barrier protects LDS-resident data only; the compiler's
// automatic s_waitcnt vmcnt(N) still guards consumption of global loads.
static __device__ __forceinline__ void barrier_lds_only() {
  asm volatile("s_waitcnt lgkmcnt(0)\n\ts_barrier" ::: "memory");
}

typedef short bf8 __attribute__((ext_vector_type(8)));
typedef float f4 __attribute__((ext_vector_type(4)));

// ---------------------------------------------------------------------------
// K0: transpose + bf16-cast projection weights: W[k][h] fp32 -> Wt[h][k] bf16
// ---------------------------------------------------------------------------
__global__ __launch_bounds__(256) void k0_wt(
    const float* __restrict__ Wb, const float* __restrict__ Wg,
    unsigned short* __restrict__ Wtb, unsigned short* __restrict__ Wtg) {
  int blk = blockIdx.x;
  const float* W = (blk < 8) ? Wb : Wg;
  unsigned short* Wt = (blk < 8) ? Wtb : Wtg;
  int k0 = (blk & 7) * 256;
  int tid = threadIdx.x;
  __shared__ unsigned short st[16][272];
  const float* p = W + (size_t)(k0 + tid) * HH;
#pragma unroll
  for (int h4 = 0; h4 < 4; h4++) {
    float4 x = *(const float4*)(p + h4 * 4);
    st[h4 * 4 + 0][tid] = f2bf(x.x);
    st[h4 * 4 + 1][tid] = f2bf(x.y);
    st[h4 * 4 + 2][tid] = f2bf(x.z);
    st[h4 * 4 + 3][tid] = f2bf(x.w);
  }
  __syncthreads();
  int h = tid >> 4, c = (tid & 15) << 4;
#pragma unroll
  for (int j = 0; j < 16; j++)
    Wt[(size_t)h * HIDD + k0 + c + j] = st[h][c + j];
}

// ---------------------------------------------------------------------------
// K1 (MFMA): beta = sigmoid(hab @ Wb), graw = hg @ Wg as skinny GEMM.
// ---------------------------------------------------------------------------
__global__ __launch_bounds__(256) void k1_beta_g(
    const float* __restrict__ hab, const float* __restrict__ hg,
    const unsigned short* __restrict__ Wtb, const unsigned short* __restrict__ Wtg,
    float* __restrict__ beta, float* __restrict__ graw) {
  int tile = blockIdx.x;               // 512 tiles of 16 tokens
  int tid = threadIdx.x;
  int w = tid >> 6, lane = tid & 63;
  int proj = w >> 1, ks = w & 1;
  int n16 = lane & 15, qd = lane >> 4;
  const float* hid = proj ? hg : hab;
  const unsigned short* Wt = proj ? Wtg : Wtb;
  size_t rowbase = (size_t)(tile * 16 + n16) * HIDD;
  int k0 = ks * 1024;

  f4 acc = {0.f, 0.f, 0.f, 0.f};
  for (int s = 0; s < 32; s++) {
    int kk = k0 + s * 32 + qd * 8;
    const float* hp = hid + rowbase + kk;
    float4 h0 = *(const float4*)hp;
    float4 h1 = *(const float4*)(hp + 4);
    bf8 a;
    a[0] = (short)f2bf(h0.x); a[1] = (short)f2bf(h0.y);
    a[2] = (short)f2bf(h0.z); a[3] = (short)f2bf(h0.w);
    a[4] = (short)f2bf(h1.x); a[5] = (short)f2bf(h1.y);
    a[6] = (short)f2bf(h1.z); a[7] = (short)f2bf(h1.w);
    bf8 b = *(const bf8*)&Wt[(size_t)n16 * HIDD + kk];
    acc = __builtin_amdgcn_mfma_f32_16x16x32_bf16(a, b, acc, 0, 0, 0);
  }

  __shared__ float red[2][16][17];
  if (ks == 1) {
#pragma unroll
    for (int r = 0; r < 4; r++) red[proj][qd * 4 + r][n16] = acc[r];
  }
  __syncthreads();
  if (ks == 0) {
#pragma unroll
    for (int r = 0; r < 4; r++) {
      float s = acc[r] + red[proj][qd * 4 + r][n16];
      size_t t = (size_t)(tile * 16 + qd * 4 + r) * HH + n16;
      if (proj == 0) beta[t] = 1.f / (1.f + expf(-s));
      else           graw[t] = s;
    }
  }
}

// ---------------------------------------------------------------------------
// K2: l2norm(q)*scale -> qn (bf16), l2norm(k) -> kn (bf16)
// ---------------------------------------------------------------------------
__global__ __launch_bounds__(256) void k2_l2norm(
    const float* __restrict__ q, const float* __restrict__ k,
    unsigned short* __restrict__ qn, unsigned short* __restrict__ kn) {
  int lane = threadIdx.x & 63, wave = threadIdx.x >> 6;
  for (int u = 0; u < 2; u++) {
    int vec = blockIdx.x * 8 + wave * 2 + u;
    size_t off = (size_t)vec * 64 + lane;
    float2 q2 = ((const float2*)q)[off];
    float2 k2 = ((const float2*)k)[off];
    float sq = q2.x * q2.x + q2.y * q2.y;
    float sk = k2.x * k2.x + k2.y * k2.y;
#pragma unroll
    for (int m = 32; m; m >>= 1) { sq += __shfl_xor(sq, m); sk += __shfl_xor(sk, m); }
    float rq = rsqrtf(sq + 1e-6f) * QSCALE;
    float rk = rsqrtf(sk + 1e-6f);
    unsigned pq = (unsigned)f2bf(q2.x * rq) | ((unsigned)f2bf(q2.y * rq) << 16);
    unsigned pk = (unsigned)f2bf(k2.x * rk) | ((unsigned)f2bf(k2.y * rk) << 16);
    ((unsigned*)qn)[off] = pq;
    ((unsigned*)kn)[off] = pk;
  }
}

// ---------------------------------------------------------------------------
// K3 (MFMA): per chunk: attn = tril(q k^T) -> Ag,
//   A = tril(k_beta k^T,-1), T = (I+A)^{-1} -> Tg via nilpotent doubling.
// ---------------------------------------------------------------------------
#define SW 72          // stride (shorts) of 64x64 bf16 mats
#define O_M0R 0        // offsets in shorts
#define O_M0T 4608
#define O_M1R 9216
#define O_M1T 13824
#define O_TB  18432    // T^T (col-major shadow of T), bf16
#define ARENA_SH 23040

__global__ __launch_bounds__(256) void k3_chunk(
    const unsigned short* __restrict__ qn, const unsigned short* __restrict__ kn,
    const float* __restrict__ beta,
    unsigned short* __restrict__ Tg, unsigned short* __restrict__ Ag) {
  int cid = blockIdx.x;
  int n = cid & (NN - 1);
  int bh = cid / NN;
  int h = bh & (HH - 1);
  int b = bh / HH;
  int tid = threadIdx.x;
  int w = tid >> 6;
  int lane = tid & 63;
  int n16 = lane & 15;
  int qd = lane >> 4;
  int r0 = w * 16;

  __shared__ __align__(16) unsigned short arena[ARENA_SH];  // 46080 B
  __shared__ float sb[CC];
  unsigned short* sk = arena;           // [c][dk] stride 136, 8704 shorts
  unsigned short* sq = arena + 8704;    // aliased by M buffers after init

  int t0 = n * CC;
#pragma unroll
  for (int p = 0; p < 4; p++) {
    int id = p * 256 + tid, row = id >> 4, c8 = (id & 15) << 3;
    size_t g = ((size_t)((b * TT + t0 + row) * HH + h)) * DKk + c8;
    *(uint4*)&sk[row * 136 + c8] = *(const uint4*)(kn + g);
    *(uint4*)&sq[row * 136 + c8] = *(const uint4*)(qn + g);
  }
  if (tid < CC) sb[tid] = beta[(size_t)((b * TT + t0 + tid) * HH + h)];
  __syncthreads();

  // ---- attn = q k^T and raw kk = k k^T   (MFMA, K=128)
  f4 at[4], mk[4];
#pragma unroll
  for (int ct = 0; ct < 4; ct++) { at[ct] = (f4){0,0,0,0}; mk[ct] = (f4){0,0,0,0}; }
#pragma unroll
  for (int s = 0; s < 4; s++) {
    bf8 aq = *(const bf8*)&sq[(r0 + n16) * 136 + s * 32 + qd * 8];
    bf8 ak = *(const bf8*)&sk[(r0 + n16) * 136 + s * 32 + qd * 8];
#pragma unroll
    for (int ct = 0; ct < 4; ct++) {
      bf8 bk = *(const bf8*)&sk[(ct * 16 + n16) * 136 + s * 32 + qd * 8];
      at[ct] = __builtin_amdgcn_mfma_f32_16x16x32_bf16(aq, bk, at[ct], 0, 0, 0);
      mk[ct] = __builtin_amdgcn_mfma_f32_16x16x32_bf16(ak, bk, mk[ct], 0, 0, 0);
    }
  }

  size_t abase = (size_t)cid * (CC * CC);
  f4 tf[4];
  float mpv[4][4];
#pragma unroll
  for (int ct = 0; ct < 4; ct++) {
#pragma unroll
    for (int r = 0; r < 4; r++) {
      int i = r0 + qd * 4 + r, j = ct * 16 + n16;
      Ag[abase + i * CC + j] = f2bf((j <= i) ? at[ct][r] : 0.f);
      float mp = (j < i) ? -sb[i] * mk[ct][r] : 0.f;
      mpv[ct][r] = mp;
      tf[ct][r] = (i == j) ? 1.f : mp;
    }
  }
  __syncthreads();   // reads of sk/sq done; arena can be re-purposed

#pragma unroll
  for (int ct = 0; ct < 4; ct++) {
#pragma unroll
    for (int r = 0; r < 4; r++) {
      int i = r0 + qd * 4 + r, j = ct * 16 + n16;
      unsigned short hm = f2bf(mpv[ct][r]);
      arena[O_M0R + i * SW + j] = hm;
      arena[O_M0T + j * SW + i] = hm;
      arena[O_TB + j * SW + i] = f2bf(tf[ct][r]);
    }
  }
  __syncthreads();

  int p = 0;
  for (int it = 1; it <= 5; it++) {
    int mrp = p ? O_M1R : O_M0R, mtp = p ? O_M1T : O_M0T;
    int mrn = p ? O_M0R : O_M1R, mtn = p ? O_M0T : O_M1T;
    f4 nr[4];
#pragma unroll
    for (int ct = 0; ct < 4; ct++) nr[ct] = (f4){0,0,0,0};
#pragma unroll
    for (int s = 0; s < 2; s++) {
      bf8 a = *(const bf8*)&arena[mrp + (r0 + n16) * SW + s * 32 + qd * 8];
#pragma unroll
      for (int ct = 0; ct < 4; ct++) {
        bf8 bb = *(const bf8*)&arena[mtp + (ct * 16 + n16) * SW + s * 32 + qd * 8];
        nr[ct] = __builtin_amdgcn_mfma_f32_16x16x32_bf16(a, bb, nr[ct], 0, 0, 0);
      }
    }
#pragma unroll
    for (int ct = 0; ct < 4; ct++) {
#pragma unroll
      for (int r = 0; r < 4; r++) {
        int i = r0 + qd * 4 + r, j = ct * 16 + n16;
        unsigned short hm = f2bf(nr[ct][r]);
        arena[mrn + i * SW + j] = hm;
        arena[mtn + j * SW + i] = hm;
      }
    }
    __syncthreads();  // B1

    // phase B: Tf += N · T
#pragma unroll
    for (int s = 0; s < 2; s++) {
      bf8 a = *(const bf8*)&arena[mrn + (r0 + n16) * SW + s * 32 + qd * 8];
#pragma unroll
      for (int ct = 0; ct < 4; ct++) {
        bf8 bb = *(const bf8*)&arena[O_TB + (ct * 16 + n16) * SW + s * 32 + qd * 8];
        tf[ct] = __builtin_amdgcn_mfma_f32_16x16x32_bf16(a, bb, tf[ct], 0, 0, 0);
      }
    }
    __syncthreads();  // B2

    if (it < 5) {
#pragma unroll
      for (int ct = 0; ct < 4; ct++) {
#pragma unroll
        for (int r = 0; r < 4; r++) {
          int i = r0 + qd * 4 + r, j = ct * 16 + n16;
          arena[O_TB + j * SW + i] = f2bf(tf[ct][r]);
        }
      }
    }
    p = 1 - p;
  }

#pragma unroll
  for (int ct = 0; ct < 4; ct++) {
#pragma unroll
    for (int r = 0; r < 4; r++) {
      int i = r0 + qd * 4 + r, j = ct * 16 + n16;
      Tg[abase + i * CC + j] = f2bf(tf[ct][r]);
    }
  }
}

// ---------------------------------------------------------------------------
// K4 (MFMA): sequential chunk scan. block = (b,h,jg), 16 DV cols, 4 waves.
// R4 changes: (1) lgkm-only barriers keep prefetch loads in flight across the
// whole chunk; (2) sk stored with 8-short groups XOR-swizzled by (row>>3)&7 so
// the S-update column gather's 4 qd groups hit disjoint bank windows.
// ---------------------------------------------------------------------------
__global__ __launch_bounds__(256) void k4_scan(
    const unsigned short* __restrict__ qn, const unsigned short* __restrict__ kn,
    const float* __restrict__ v, const float* __restrict__ beta,
    const unsigned short* __restrict__ Tg, const unsigned short* __restrict__ Ag,
    float* __restrict__ o) {
  int bi = blockIdx.x;                 // jg*32 + bh
  int jg = bi >> 5;
  int bh = bi & 31;
  int h = bh & (HH - 1);
  int b = bh >> 4;
  int tid = threadIdx.x;
  int j0 = jg * 16;
  int w = tid >> 6;
  int lane = tid & 63;
  int n16 = lane & 15;
  int qd = lane >> 4;
  int r0 = w * 16;                     // chunk-row tile of this wave
  int dkbase = w * 32;                 // S dk-rows owned by this wave

  __shared__ __align__(16) unsigned short sk[CC * 136];   // 17408 B [c][dk] (swizzled groups)
  __shared__ __align__(16) unsigned short sq[CC * 136];   // 17408 B
  __shared__ __align__(16) unsigned short sT[CC * 72];    //  9216 B [i][j]
  __shared__ __align__(16) unsigned short sA[CC * 72];    //  9216 B
  __shared__ __align__(16) unsigned short sSb[16 * 136];  //  4352 B S^T: [col][dk]
  __shared__ __align__(16) unsigned short sxT[16 * 72];   //  2304 B x^T: [col][c]
  __shared__ __align__(16) unsigned short svT[16 * 72];   //  2304 B vi^T
  __shared__ float sb[CC];                                //   256 B

  f4 S0 = {0.f, 0.f, 0.f, 0.f}, S1 = {0.f, 0.f, 0.f, 0.f};
  for (int i = tid; i < 16 * 136; i += 256) sSb[i] = 0;

  int bhBase = (b * HH + h) * NN;

  uint4 pk[4], pq[4], pt[2], pa[2];
  float4 pv;
  float pb = 0.f;

  // A-fragment swizzled group offset for this lane's sk row reads
  int rowA = r0 + n16;                       // row used in x-compute A-frags
  int swzA = ((rowA >> 3) & 7);

  // prefetch chunk 0
  {
#pragma unroll
    for (int p = 0; p < 4; p++) {
      int id = p * 256 + tid, row = id >> 4, c8 = (id & 15) << 3;
      size_t g = ((size_t)((b * TT + row) * HH + h)) * DKk + c8;
      pk[p] = *(const uint4*)(kn + g);
      pq[p] = *(const uint4*)(qn + g);
    }
    size_t cb = (size_t)bhBase * (CC * CC);
#pragma unroll
    for (int p = 0; p < 2; p++) {
      int id = p * 256 + tid, row = id >> 3, c8 = (id & 7) << 3;
      pt[p] = *(const uint4*)(Tg + cb + row * CC + c8);
      pa[p] = *(const uint4*)(Ag + cb + row * CC + c8);
    }
    {
      int c = tid >> 2, c4 = (tid & 3) << 2;
      pv = *(const float4*)(v + ((size_t)((b * TT + c) * HH + h)) * DVv + j0 + c4);
    }
    if (tid < CC) pb = beta[(size_t)((b * TT + tid) * HH + h)];
  }

  for (int n = 0; n < NN; n++) {
    int t0 = n * CC;
    // ---- stage regs -> LDS (sk group-swizzled)
#pragma unroll
    for (int p = 0; p < 4; p++) {
      int id = p * 256 + tid, row = id >> 4, g = id & 15;
      int gk = (g ^ ((row >> 3) & 7)) << 3;
      *(uint4*)&sk[row * 136 + gk] = pk[p];
      *(uint4*)&sq[row * 136 + (g << 3)] = pq[p];
    }
#pragma unroll
    for (int p = 0; p < 2; p++) {
      int id = p * 256 + tid, row = id >> 3, c8 = (id & 7) << 3;
      *(uint4*)&sT[row * 72 + c8] = pt[p];
      *(uint4*)&sA[row * 72 + c8] = pa[p];
    }
    {
      int c = tid >> 2, c4 = (tid & 3) << 2;
      sxT[(c4 + 0) * 72 + c] = f2bf(pv.x);
      sxT[(c4 + 1) * 72 + c] = f2bf(pv.y);
      sxT[(c4 + 2) * 72 + c] = f2bf(pv.z);
      sxT[(c4 + 3) * 72 + c] = f2bf(pv.w);
    }
    if (tid < CC) sb[tid] = pb;
    barrier_lds_only();   // B1: staging visible (LDS only)

    // ---- prefetch next chunk into regs (stays in flight across B2..B4+B1)
    if (n + 1 < NN) {
      int t0n = t0 + CC;
#pragma unroll
      for (int p = 0; p < 4; p++) {
        int id = p * 256 + tid, row = id >> 4, c8 = (id & 15) << 3;
        size_t g = ((size_t)((b * TT + t0n + row) * HH + h)) * DKk + c8;
        pk[p] = *(const uint4*)(kn + g);
        pq[p] = *(const uint4*)(qn + g);
      }
      size_t cb = (size_t)(bhBase + n + 1) * (CC * CC);
#pragma unroll
      for (int p = 0; p < 2; p++) {
        int id = p * 256 + tid, row = id >> 3, c8 = (id & 7) << 3;
        pt[p] = *(const uint4*)(Tg + cb + row * CC + c8);
        pa[p] = *(const uint4*)(Ag + cb + row * CC + c8);
      }
      {
        int c = tid >> 2, c4 = (tid & 3) << 2;
        pv = *(const float4*)(v + ((size_t)((b * TT + t0n + c) * HH + h)) * DVv + j0 + c4);
      }
      if (tid < CC) pb = beta[(size_t)((b * TT + t0n + tid) * HH + h)];
    }

    // ---- x^T = beta * (v - k@S)^T   (in-place in sxT)
    {
      f4 acc = {0.f, 0.f, 0.f, 0.f};
#pragma unroll
      for (int s = 0; s < 4; s++) {
        bf8 a = *(const bf8*)&sk[rowA * 136 + (((s * 4 + qd) ^ swzA) << 3)];
        bf8 bb = *(const bf8*)&sSb[n16 * 136 + s * 32 + qd * 8];
        acc = __builtin_amdgcn_mfma_f32_16x16x32_bf16(a, bb, acc, 0, 0, 0);
      }
#pragma unroll
      for (int r = 0; r < 4; r++) {
        int c = r0 + qd * 4 + r;
        float vval = bf2f(sxT[n16 * 72 + c]);
        sxT[n16 * 72 + c] = f2bf(sb[c] * (vval - acc[r]));
      }
    }
    barrier_lds_only();   // B2

    // ---- vi = T @ x -> svT (bf16, transposed)
    {
      f4 acc = {0.f, 0.f, 0.f, 0.f};
#pragma unroll
      for (int s = 0; s < 2; s++) {
        bf8 a = *(const bf8*)&sT[(r0 + n16) * 72 + s * 32 + qd * 8];
        bf8 bb = *(const bf8*)&sxT[n16 * 72 + s * 32 + qd * 8];
        acc = __builtin_amdgcn_mfma_f32_16x16x32_bf16(a, bb, acc, 0, 0, 0);
      }
#pragma unroll
      for (int r = 0; r < 4; r++) {
        int c = r0 + qd * 4 + r;
        svT[n16 * 72 + c] = f2bf(acc[r]);
      }
    }
    barrier_lds_only();   // B3

    // ---- o = q@S_old + attn@vi -> global
    {
      f4 acc = {0.f, 0.f, 0.f, 0.f};
#pragma unroll
      for (int s = 0; s < 4; s++) {
        bf8 a = *(const bf8*)&sq[(r0 + n16) * 136 + s * 32 + qd * 8];
        bf8 bb = *(const bf8*)&sSb[n16 * 136 + s * 32 + qd * 8];
        acc = __builtin_amdgcn_mfma_f32_16x16x32_bf16(a, bb, acc, 0, 0, 0);
      }
#pragma unroll
      for (int s = 0; s < 2; s++) {
        bf8 a = *(const bf8*)&sA[(r0 + n16) * 72 + s * 32 + qd * 8];
        bf8 bb = *(const bf8*)&svT[n16 * 72 + s * 32 + qd * 8];
        acc = __builtin_amdgcn_mfma_f32_16x16x32_bf16(a, bb, acc, 0, 0, 0);
      }
#pragma unroll
      for (int r = 0; r < 4; r++) {
        int c = r0 + qd * 4 + r;
        o[((size_t)((b * TT + t0 + c) * HH + h)) * DVv + j0 + n16] = acc[r];
      }
    }

    // ---- S += k^T @ vi   (register accumulators, per-wave dk rows)
    {
#pragma unroll
      for (int t = 0; t < 2; t++) {
        int dkt = dkbase + t * 16;
        int col = dkt + n16;
        int gg = col >> 3, co = col & 7;
        f4 acc = t ? S1 : S0;
#pragma unroll
        for (int s = 0; s < 2; s++) {
          int sq8 = (s * 4 + qd) & 7;    // (row>>3)&7 for rows s*32+qd*8+j
          bf8 a;
#pragma unroll
          for (int j = 0; j < 8; j++)
            a[j] = (short)sk[(s * 32 + qd * 8 + j) * 136 + (((gg ^ sq8) << 3) | co)];
          bf8 bb = *(const bf8*)&svT[n16 * 72 + s * 32 + qd * 8];
          acc = __builtin_amdgcn_mfma_f32_16x16x32_bf16(a, bb, acc, 0, 0, 0);
        }
        if (t) S1 = acc; else S0 = acc;
      }
    }
    barrier_lds_only();   // B4

    // ---- write new S (bf16) to sSb
#pragma unroll
    for (int r = 0; r < 4; r++) {
      sSb[n16 * 136 + dkbase + qd * 4 + r] = f2bf(S0[r]);
      sSb[n16 * 136 + dkbase + 16 + qd * 4 + r] = f2bf(S1[r]);
    }
  }
}

// ---------------------------------------------------------------------------
// K5: in-place on d_out: RMSNorm(o)*o_norm_w * swish(g), then per-head
//     projection out[t, h*128+d] = sum_v o~[v] * P[h,v,d].
// ---------------------------------------------------------------------------
__global__ __launch_bounds__(256) void k5_out(
    const float* __restrict__ graw, const float* __restrict__ onw,
    const float* __restrict__ opw, float* __restrict__ out) {
  int bi = blockIdx.x;                  // B*(T/32)*H = 4096
  int h = bi & (HH - 1);
  int tt = (bi >> 4) & 127;
  int b = bi >> 11;
  int t0 = tt * 32;
  int tid = threadIdx.x;

  __shared__ __align__(16) unsigned short sP[DVv * DKk];  // 32768 B (bf16)
  __shared__ __align__(16) float so[32 * 129];            // 16512 B
  __shared__ float smul[32];
  __shared__ float snw[DVv];

  const float* P = opw + (size_t)h * DVv * DKk;
  for (int r = 0; r < 16; r++) {
    int idx4 = r * 256 + tid;           // 4096 quads
    float4 pvv = *(const float4*)(P + ((size_t)idx4 << 2));
    unsigned p0 = (unsigned)f2bf(pvv.x) | ((unsigned)f2bf(pvv.y) << 16);
    unsigned p1 = (unsigned)f2bf(pvv.z) | ((unsigned)f2bf(pvv.w) << 16);
    *(uint2*)&sP[idx4 << 2] = make_uint2(p0, p1);
  }
  for (int r = 0; r < 16; r++) {
    int idx = r * 256 + tid;
    int t = idx >> 7, d = idx & 127;
    so[t * 129 + d] = out[((size_t)((b * TT + t0 + t) * HH + h)) * DVv + d];
  }
  if (tid < DVv) snw[tid] = onw[tid];
  __syncthreads();

  {
    int t = tid >> 3, l8 = tid & 7;
    float ss = 0.f;
    for (int j = 0; j < 16; j++) { float x = so[t * 129 + l8 + (j << 3)]; ss += x * x; }
    ss += __shfl_down(ss, 4, 8);
    ss += __shfl_down(ss, 2, 8);
    ss += __shfl_down(ss, 1, 8);
    if (l8 == 0) {
      float rms = rsqrtf(ss * (1.f / 128.f) + 1e-5f);
      float gv = graw[(size_t)((b * TT + t0 + t) * HH + h)];
      float sig = 1.f / (1.f + expf(-gv));
      smul[t] = rms * gv * sig;
    }
  }
  __syncthreads();
  for (int r = 0; r < 16; r++) {
    int idx = r * 256 + tid;
    int t = idx >> 7, d = idx & 127;
    so[t * 129 + d] *= smul[t] * snw[d];
  }
  __syncthreads();

  {
    int ttile = tid >> 5;               // 4 tokens each
    int dt = tid & 31;                  // 4 output dims each
    int tb = ttile << 2;
    int d0 = dt << 2;
    float acc[4][4];
#pragma unroll
    for (int a = 0; a < 4; a++)
#pragma unroll
      for (int e = 0; e < 4; e++) acc[a][e] = 0.f;
    for (int vv = 0; vv < DVv; vv++) {
      uint2 u = *(const uint2*)&sP[vv * DKk + d0];
      float p0 = __uint_as_float(u.x << 16);
      float p1 = __uint_as_float(u.x & 0xffff0000u);
      float p2 = __uint_as_float(u.y << 16);
      float p3 = __uint_as_float(u.y & 0xffff0000u);
#pragma unroll
      for (int a = 0; a < 4; a++) {
        float ov = so[(tb + a) * 129 + vv];
        acc[a][0] += ov * p0; acc[a][1] += ov * p1; acc[a][2] += ov * p2; acc[a][3] += ov * p3;
      }
    }
#pragma unroll
    for (int a = 0; a < 4; a++) {
      size_t go = ((size_t)((b * TT + t0 + tb + a) * HH + h)) * DKk + d0;
      float4 r; r.x = acc[a][0]; r.y = acc[a][1]; r.z = acc[a][2]; r.w = acc[a][3];
      *(float4*)(out + go) = r;
    }
  }
}

// ---------------------------------------------------------------------------
extern "C" void kernel_launch(void* const* d_in, const int* in_sizes, int n_in,
                              void* d_out, int out_size, void* d_ws, size_t ws_size,
                              hipStream_t stream) {
  (void)in_sizes; (void)n_in; (void)out_size; (void)ws_size;
  const float* hab = (const float*)d_in[0];
  const float* hg  = (const float*)d_in[1];
  const float* q   = (const float*)d_in[2];
  const float* k   = (const float*)d_in[3];
  const float* v   = (const float*)d_in[4];
  const float* Wb  = (const float*)d_in[5];
  const float* Wg  = (const float*)d_in[6];
  const float* onw = (const float*)d_in[7];
  const float* opw = (const float*)d_in[8];
  float* out = (float*)d_out;

  // ws layout (bytes): beta 512K | graw 512K | qn 32M | kn 32M | T 16M | attn 16M
  //                    | Wtb 64K | Wtg 64K
  char* ws = (char*)d_ws;
  float* beta          = (float*)(ws);
  float* graw          = (float*)(ws + 524288);
  unsigned short* qn   = (unsigned short*)(ws + 1048576);
  unsigned short* kn   = (unsigned short*)(ws + 34603008);
  unsigned short* Tg   = (unsigned short*)(ws + 68157440);
  unsigned short* Ag   = (unsigned short*)(ws + 84934656);
  unsigned short* Wtb  = (unsigned short*)(ws + 101711872);
  unsigned short* Wtg  = (unsigned short*)(ws + 101777408);

  hipLaunchKernelGGL(k0_wt, dim3(16), dim3(256), 0, stream,
                     Wb, Wg, Wtb, Wtg);
  hipLaunchKernelGGL(k1_beta_g, dim3(TT * BB / 16), dim3(256), 0, stream,
                     hab, hg, Wtb, Wtg, beta, graw);
  hipLaunchKernelGGL(k2_l2norm, dim3(BB * TT * HH / 8), dim3(256), 0, stream,
                     q, k, qn, kn);
  hipLaunchKernelGGL(k3_chunk, dim3(BB * HH * NN), dim3(256), 0, stream,
                     qn, kn, beta, Tg, Ag);
  hipLaunchKernelGGL(k4_scan, dim3(BB * HH * GG), dim3(256), 0, stream,
                     qn, kn, v, beta, Tg, Ag, out);
  hipLaunchKernelGGL(k5_out, dim3(BB * (TT / 32) * HH), dim3(256), 0, stream,
                     graw, onw, opw, out);
}